// Round 3
// baseline (290.440 us; speedup 1.0000x reference)
//
#include <hip/hip_runtime.h>
#include <math.h>

// Problem constants (match reference setup_inputs)
constexpr int B = 2;
constexpr int N = 4096;
constexpr int C = 32;
constexpr int D = 256;
constexpr int K = 16;
constexpr int NW = N / 32;   // adjacency bitmask words per row = 128
constexpr int CAP = 128;     // max neighbors per row (16 out + in-degree)
constexpr int ROWS = B * N;  // 8192

// ---------------------------------------------------------------------------
// Kernel 1: per-row preprocess: centers(+sqnorm or INF if invalid), feature
// inv-norm. One wave (64 lanes) per row.
__global__ void pre_kernel(const float* __restrict__ rois,
                           const float* __restrict__ feats,
                           float4* __restrict__ centers4,
                           float* __restrict__ invnorm) {
    const int t = threadIdx.x;
    const int wid = t >> 6, lane = t & 63;
    const int r = blockIdx.x * 4 + wid;
    if (r >= ROWS) return;

    const float4* f4 = reinterpret_cast<const float4*>(feats) + (size_t)r * (D / 4);
    float4 v = f4[lane];
    float ss = v.x * v.x + v.y * v.y + v.z * v.z + v.w * v.w;
#pragma unroll
    for (int off = 32; off; off >>= 1) ss += __shfl_xor(ss, off);

    if (lane == 0) {
        invnorm[r] = 1.0f / fmaxf(sqrtf(ss), 1e-6f);
        const float* rp = rois + (size_t)r * 6;
        float a0 = rp[0], a1 = rp[1], a2 = rp[2], a3 = rp[3], a4 = rp[4], a5 = rp[5];
        float cx = (a0 + a3) * 0.5f, cy = (a1 + a4) * 0.5f, cz = (a2 + a5) * 0.5f;
        float sq = cx * cx + cy * cy + cz * cz;
        float s = fabsf(a0) + fabsf(a1) + fabsf(a2) + fabsf(a3) + fabsf(a4) + fabsf(a5);
        centers4[r] = make_float4(cx, cy, cz, (s > 0.0f) ? sq : INFINITY);
    }
}

// ---------------------------------------------------------------------------
// Kernel 2: brute-force 16-NN, one wave per row, 4 rows (waves) per block.
// Centers staged in LDS as SoA (64 KB, conflict-free stride-4B reads).
// Each lane owns 64 candidates (m = lane + 64*j) and keeps only a top-2 in
// registers (no d[] array -> no scratch spill). Wave argmin on packed u64
// keys (dist_bits<<32 | index => tie-break on smaller index is free).
// Re-extraction of an exhausted lane triggers a rare LDS rescan gated by
// __any, skipping a 64-bit removed mask.
__global__ __launch_bounds__(256, 2) void knn_kernel(const float4* __restrict__ centers4,
                                                     unsigned* __restrict__ adj) {
    __shared__ float sx[N], sy[N], sz[N], sw[N];

    const int t = threadIdx.x;
    const int lane = t & 63;
    const int r = blockIdx.x * 4 + (t >> 6);
    const int n = r & (N - 1);
    const int base = r - n;

    for (int i = t; i < N; i += 256) {
        float4 c = centers4[base + i];
        sx[i] = c.x; sy[i] = c.y; sz[i] = c.z; sw[i] = c.w;
    }
    __syncthreads();

    const float cx = sx[n], cy = sy[n], cz = sz[n], cw = sw[n];

    // initial scan: per-lane top-2 (dist, j)
    float bd1 = INFINITY, bd2 = INFINITY; int bj1 = 0, bj2 = 0;
#pragma unroll 4
    for (int j = 0; j < 64; ++j) {
        const int m = lane + (j << 6);
        float dist = fmaxf(cw + sw[m] - 2.0f * (cx * sx[m] + cy * sy[m] + cz * sz[m]), 0.0f);
        dist = (m == n) ? INFINITY : dist;
        if (dist < bd1)      { bd2 = bd1; bj2 = bj1; bd1 = dist; bj1 = j; }
        else if (dist < bd2) { bd2 = dist; bj2 = j; }
    }
    bool have2 = true;

    unsigned long long removed = 0ull;
    const unsigned long long KINF = (unsigned long long)0x7F800000u << 32;
    int my_sel = -1;

    for (int round = 0; round < K; ++round) {
        unsigned long long k =
            ((unsigned long long)__float_as_uint(bd1) << 32) | (unsigned)(lane + (bj1 << 6));
#pragma unroll
        for (int off = 32; off; off >>= 1) {
            unsigned long long o = __shfl_xor(k, off);
            k = (o < k) ? o : k;
        }
        if (k >= KINF) break;                 // uniform: no finite candidates left
        const int wm = (int)(unsigned)k;      // winner index within batch
        if (lane == round) my_sel = wm;

        if ((wm & 63) == lane) {              // this lane owned the winner
            removed |= 1ull << bj1;
            if (have2) { bd1 = bd2; bj1 = bj2; have2 = false; }
            else       { bd1 = -1.0f; }       // sentinel: needs rescan
        }
        const bool need = ((wm & 63) == lane) && (bd1 < 0.0f);
        if (__any(need)) {
            if (need) {
                float nb1 = INFINITY, nb2 = INFINITY; int nj1 = 0, nj2 = 0;
#pragma unroll 4
                for (int j = 0; j < 64; ++j) {
                    const int m = lane + (j << 6);
                    float dj = fmaxf(cw + sw[m] - 2.0f * (cx * sx[m] + cy * sy[m] + cz * sz[m]), 0.0f);
                    bool skip = ((removed >> j) & 1ull) || (m == n);
                    dj = skip ? INFINITY : dj;
                    if (dj < nb1)      { nb2 = nb1; nj2 = nj1; nb1 = dj; nj1 = j; }
                    else if (dj < nb2) { nb2 = dj; nj2 = j; }
                }
                bd1 = nb1; bj1 = nj1; bd2 = nb2; bj2 = nj2;
                have2 = (nb2 < INFINITY);
            }
        }
    }

    if (my_sel >= 0) {
        const int m = my_sel;
        atomicOr(&adj[(size_t)r * NW + (m >> 5)], 1u << (m & 31));
        atomicOr(&adj[(size_t)(base + m) * NW + (n >> 5)], 1u << (n & 31));
    }
}

// ---------------------------------------------------------------------------
// Kernel 3: build weighted neighbor lists from adjacency bits.
__global__ void build_kernel(const float* __restrict__ feats,
                             const float4* __restrict__ centers4,
                             const float* __restrict__ invnorm,
                             const unsigned* __restrict__ adj,
                             int* __restrict__ nbr_idx,
                             float* __restrict__ nbr_w,
                             int* __restrict__ nbr_cnt,
                             const float* __restrict__ raw_sigma) {
    const int t = threadIdx.x;
    const int r = blockIdx.x;
    const int base = r - (r & (N - 1));

    __shared__ int    s_off[NW];
    __shared__ int    s_list[CAP];
    __shared__ float  s_w[CAP];
    __shared__ float4 s_fq[D / 4];
    __shared__ int    s_cnt;
    __shared__ float  s_sum;

    const float4* fq4 = reinterpret_cast<const float4*>(feats) + (size_t)r * (D / 4);
    if (t < D / 4) s_fq[t] = fq4[t];

    unsigned word = 0;
    if (t < NW) {
        word = adj[(size_t)r * NW + t];
        s_off[t] = __popc(word);
    }
    __syncthreads();
    if (t == 0) {
        int run = 0;
        for (int i = 0; i < NW; ++i) { int c = s_off[i]; s_off[i] = run; run += c; }
        s_cnt = run > CAP ? CAP : run;
    }
    __syncthreads();
    const int cnt = s_cnt;
    if (t < NW && word) {
        int o = s_off[t];
        unsigned w2 = word;
        while (w2) {
            int bit = __ffs(w2) - 1;
            if (o < CAP) s_list[o] = t * 32 + bit;
            ++o;
            w2 &= w2 - 1;
        }
    }
    __syncthreads();

    const float rs = raw_sigma[0];
    const float sigma = fmaxf(log1pf(expf(rs)), 1e-6f);
    const float nhalf_inv_s2 = -0.5f / (sigma * sigma);

    const int wid = t >> 6, lane = t & 63;
    const float inq = invnorm[r];
    const float4 cq = centers4[r];

    for (int i = wid; i < cnt; i += 4) {
        int m = s_list[i];
        int gm = base + m;
        float4 fm = reinterpret_cast<const float4*>(feats)[(size_t)gm * (D / 4) + lane];
        float4 fq = s_fq[lane];
        float p = fm.x * fq.x + fm.y * fq.y + fm.z * fq.z + fm.w * fq.w;
#pragma unroll
        for (int off = 32; off; off >>= 1) p += __shfl_xor(p, off);
        if (lane == 0) {
            float cosv = p * inq * invnorm[gm];
            float aff = fminf(fmaxf((cosv + 1.0f) * 0.5f, 0.0f), 1.0f);
            float4 cm = centers4[gm];
            float dist = fmaxf(cq.w + cm.w - 2.0f * (cq.x * cm.x + cq.y * cm.y + cq.z * cm.z), 0.0f);
            s_w[i] = expf(dist * nhalf_inv_s2) * aff;
        }
    }
    __syncthreads();
    if (t == 0) {
        float sum = 0.0f;
        for (int i = 0; i < cnt; ++i) sum += s_w[i];
        s_sum = fmaxf(sum, 1e-6f);
    }
    __syncthreads();
    for (int i = t; i < cnt; i += 256) {
        nbr_idx[(size_t)r * CAP + i] = s_list[i];
        nbr_w[(size_t)r * CAP + i]   = s_w[i] / s_sum;
    }
    if (t == 0) nbr_cnt[r] = cnt;
}

// ---------------------------------------------------------------------------
// Kernel 4: q = softmax(logits) rows. 32 lanes per row, 8 rows per block.
__global__ void softmax_kernel(const float* __restrict__ logits, float* __restrict__ q) {
    const int t = threadIdx.x;
    const int r = blockIdx.x * 8 + (t >> 5);
    const int c = t & 31;
    float x = logits[(size_t)r * C + c];
    float mx = x;
#pragma unroll
    for (int off = 16; off; off >>= 1) mx = fmaxf(mx, __shfl_xor(mx, off, 32));
    float e = expf(x - mx);
    float s = e;
#pragma unroll
    for (int off = 16; off; off >>= 1) s += __shfl_xor(s, off, 32);
    q[(size_t)r * C + c] = e / s;
}

// ---------------------------------------------------------------------------
// Kernel 5: one mean-field iteration. 32 lanes per row (class c per lane).
__global__ void iter_kernel(const float* __restrict__ logits,
                            const int* __restrict__ nbr_idx,
                            const float* __restrict__ nbr_w,
                            const int* __restrict__ nbr_cnt,
                            const float* __restrict__ q_in,
                            float* __restrict__ q_out,
                            float* __restrict__ refined_out,
                            const float* __restrict__ raw_smooth,
                            int write_refined) {
    const int t = threadIdx.x;
    const int r = blockIdx.x * 8 + (t >> 5);
    const int c = t & 31;
    const int base = r - (r & (N - 1));
    const float smooth = log1pf(expf(raw_smooth[0]));

    const int cnt = nbr_cnt[r];
    const int*   ip = nbr_idx + (size_t)r * CAP;
    const float* wp = nbr_w  + (size_t)r * CAP;

    float qn = 0.0f;
    for (int j = 0; j < cnt; ++j) {
        int m = ip[j];
        float w = wp[j];
        qn += w * q_in[(size_t)(base + m) * C + c];
    }

    const float fc = (float)c;
    float m0 = qn, m1 = qn * fc, m2 = qn * fc * fc;
#pragma unroll
    for (int off = 16; off; off >>= 1) {
        m0 += __shfl_xor(m0, off, 32);
        m1 += __shfl_xor(m1, off, 32);
        m2 += __shfl_xor(m2, off, 32);
    }
    float pw = (m2 - 2.0f * fc * m1 + fc * fc * m0) * (1.0f / 961.0f);
    float refined = logits[(size_t)r * C + c] - smooth * pw;
    if (write_refined) refined_out[(size_t)r * C + c] = refined;

    float mx = refined;
#pragma unroll
    for (int off = 16; off; off >>= 1) mx = fmaxf(mx, __shfl_xor(mx, off, 32));
    float e = expf(refined - mx);
    float s = e;
#pragma unroll
    for (int off = 16; off; off >>= 1) s += __shfl_xor(s, off, 32);
    q_out[(size_t)r * C + c] = e / s;
}

// ---------------------------------------------------------------------------
extern "C" void kernel_launch(void* const* d_in, const int* in_sizes, int n_in,
                              void* d_out, int out_size, void* d_ws, size_t ws_size,
                              hipStream_t stream) {
    const float* logits     = (const float*)d_in[0];
    const float* rois       = (const float*)d_in[1];
    const float* feats      = (const float*)d_in[2];
    const float* raw_sigma  = (const float*)d_in[3];
    const float* raw_smooth = (const float*)d_in[4];
    float* out = (float*)d_out;

    char* ws = (char*)d_ws;
    size_t off = 0;
    auto alloc = [&](size_t bytes) -> void* {
        void* p = ws + off;
        off += (bytes + 255) & ~(size_t)255;
        return p;
    };
    float4*   centers4 = (float4*)  alloc((size_t)ROWS * sizeof(float4));
    float*    invnorm  = (float*)   alloc((size_t)ROWS * 4);
    unsigned* adj      = (unsigned*)alloc((size_t)ROWS * NW * 4);
    int*      nbr_idx  = (int*)     alloc((size_t)ROWS * CAP * 4);
    float*    nbr_w    = (float*)   alloc((size_t)ROWS * CAP * 4);
    int*      nbr_cnt  = (int*)     alloc((size_t)ROWS * 4);
    float*    q_a      = (float*)   alloc((size_t)ROWS * C * 4);
    float*    q_b      = (float*)   alloc((size_t)ROWS * C * 4);

    hipMemsetAsync(adj, 0, (size_t)ROWS * NW * 4, stream);
    pre_kernel<<<ROWS / 4, 256, 0, stream>>>(rois, feats, centers4, invnorm);
    knn_kernel<<<ROWS / 4, 256, 0, stream>>>(centers4, adj);
    build_kernel<<<ROWS, 256, 0, stream>>>(feats, centers4, invnorm, adj,
                                           nbr_idx, nbr_w, nbr_cnt, raw_sigma);
    softmax_kernel<<<ROWS / 8, 256, 0, stream>>>(logits, q_a);

    float* qi = q_a;
    float* qo = q_b;
    for (int it = 0; it < 5; ++it) {
        iter_kernel<<<ROWS / 8, 256, 0, stream>>>(logits, nbr_idx, nbr_w, nbr_cnt,
                                                  qi, qo, out, raw_smooth,
                                                  (it == 4) ? 1 : 0);
        float* tmp = qi; qi = qo; qo = tmp;
    }
}

// Round 4
// 172.690 us; speedup vs baseline: 1.6819x; 1.6819x over previous
//
#include <hip/hip_runtime.h>
#include <math.h>

// Problem constants (match reference setup_inputs)
constexpr int B = 2;
constexpr int N = 4096;
constexpr int C = 32;
constexpr int D = 256;
constexpr int K = 16;
constexpr int NW = N / 32;   // adjacency bitmask words per row = 128
constexpr int CAP = 128;     // max neighbors per row (16 out + in-degree)
constexpr int ROWS = B * N;  // 8192

// ---------------------------------------------------------------------------
// Kernel 1: per-row preprocess: centers(+sqnorm or INF if invalid), feature
// inv-norm. One wave (64 lanes) per row.
__global__ void pre_kernel(const float* __restrict__ rois,
                           const float* __restrict__ feats,
                           float4* __restrict__ centers4,
                           float* __restrict__ invnorm) {
    const int t = threadIdx.x;
    const int wid = t >> 6, lane = t & 63;
    const int r = blockIdx.x * 4 + wid;
    if (r >= ROWS) return;

    const float4* f4 = reinterpret_cast<const float4*>(feats) + (size_t)r * (D / 4);
    float4 v = f4[lane];
    float ss = v.x * v.x + v.y * v.y + v.z * v.z + v.w * v.w;
#pragma unroll
    for (int off = 32; off; off >>= 1) ss += __shfl_xor(ss, off);

    if (lane == 0) {
        invnorm[r] = 1.0f / fmaxf(sqrtf(ss), 1e-6f);
        const float* rp = rois + (size_t)r * 6;
        float a0 = rp[0], a1 = rp[1], a2 = rp[2], a3 = rp[3], a4 = rp[4], a5 = rp[5];
        float cx = (a0 + a3) * 0.5f, cy = (a1 + a4) * 0.5f, cz = (a2 + a5) * 0.5f;
        float sq = cx * cx + cy * cy + cz * cz;
        float s = fabsf(a0) + fabsf(a1) + fabsf(a2) + fabsf(a3) + fabsf(a4) + fabsf(a5);
        centers4[r] = make_float4(cx, cy, cz, (s > 0.0f) ? sq : INFINITY);
    }
}

// ---------------------------------------------------------------------------
// Kernel 2: brute-force 16-NN. 1024 threads = 16 rows (one wave each) share
// one 64KB LDS SoA center table -> 2 blocks/CU (128KB LDS), VGPR capped at 64
// via launch_bounds => 8 waves/SIMD occupancy. Each lane owns 64 candidates
// (m = lane + 64*j), keeps a top-3 in registers. Selection rounds reduce a
// 32-bit float dist (6 chained shfl), find the owner by ballot (unique-owner
// fast path; exact-tie path does an index-min reduce => lax.top_k tie order).
// Lane exhaustion (3 extractions) triggers a rare LDS rescan gated by __any.
__global__ __launch_bounds__(1024, 8) void knn_kernel(const float4* __restrict__ centers4,
                                                      unsigned* __restrict__ adj) {
    __shared__ float sx[N], sy[N], sz[N], sw[N];

    const int t = threadIdx.x;
    const int lane = t & 63;
    const int r = blockIdx.x * 16 + (t >> 6);
    const int n = r & (N - 1);
    const int base = r - n;

    for (int i = t; i < N; i += 1024) {
        float4 c = centers4[base + i];
        sx[i] = c.x; sy[i] = c.y; sz[i] = c.z; sw[i] = c.w;
    }
    __syncthreads();

    const float cx = sx[n], cy = sy[n], cz = sz[n], cw = sw[n];

    // initial scan: per-lane top-3 (dist, j), branchless-ish inserts
    float bd1 = INFINITY, bd2 = INFINITY, bd3 = INFINITY;
    int   bj1 = 0,        bj2 = 0,        bj3 = 0;
#pragma unroll 2
    for (int j = 0; j < 64; ++j) {
        const int m = lane + (j << 6);
        float dist = fmaxf(cw + sw[m] - 2.0f * (cx * sx[m] + cy * sy[m] + cz * sz[m]), 0.0f);
        dist = (m == n) ? INFINITY : dist;
        if (dist < bd1)      { bd3 = bd2; bj3 = bj2; bd2 = bd1; bj2 = bj1; bd1 = dist; bj1 = j; }
        else if (dist < bd2) { bd3 = bd2; bj3 = bj2; bd2 = dist; bj2 = j; }
        else if (dist < bd3) { bd3 = dist; bj3 = j; }
    }

    unsigned long long removed = 0ull;
    int my_sel = -1;

    for (int round = 0; round < K; ++round) {
        // wave-min of per-lane bd1 (32-bit chain)
        float md = bd1;
#pragma unroll
        for (int off = 32; off; off >>= 1) md = fminf(md, __shfl_xor(md, off));
        if (md == INFINITY) break;            // uniform: no finite candidates left

        unsigned long long tied = __ballot(bd1 == md);
        int wm;
        if (__popcll(tied) == 1) {            // unique owner (common case)
            int wl = __ffsll((unsigned long long)tied) - 1;
            wm = __shfl((bj1 << 6) | lane, wl);
        } else {                              // exact tie: smallest index wins
            int kk = (bd1 == md) ? ((bj1 << 6) | lane) : 0x7FFFFFFF;
#pragma unroll
            for (int off = 32; off; off >>= 1) kk = min(kk, __shfl_xor(kk, off));
            wm = kk;
        }
        if (lane == round) my_sel = wm;

        if ((wm & 63) == lane) {              // this lane owned the winner
            removed |= 1ull << bj1;
            bd1 = bd2; bj1 = bj2;
            bd2 = bd3; bj2 = bj3;
            bd3 = INFINITY; bj3 = -1;         // marker: cache slot empty
        }
        const bool need = ((wm & 63) == lane) && (bj1 < 0);
        if (__any(need)) {
            if (need) {
                float nb1 = INFINITY, nb2 = INFINITY, nb3 = INFINITY;
                int   nj1 = 0,        nj2 = 0,        nj3 = 0;
#pragma unroll 2
                for (int j = 0; j < 64; ++j) {
                    const int m = lane + (j << 6);
                    float dj = fmaxf(cw + sw[m] - 2.0f * (cx * sx[m] + cy * sy[m] + cz * sz[m]), 0.0f);
                    bool skip = ((removed >> j) & 1ull) || (m == n);
                    dj = skip ? INFINITY : dj;
                    if (dj < nb1)      { nb3 = nb2; nj3 = nj2; nb2 = nb1; nj2 = nj1; nb1 = dj; nj1 = j; }
                    else if (dj < nb2) { nb3 = nb2; nj3 = nj2; nb2 = dj; nj2 = j; }
                    else if (dj < nb3) { nb3 = dj; nj3 = j; }
                }
                bd1 = nb1; bj1 = nj1; bd2 = nb2; bj2 = nj2; bd3 = nb3; bj3 = nj3;
            }
        }
    }

    if (my_sel >= 0) {
        const int m = my_sel;
        atomicOr(&adj[(size_t)r * NW + (m >> 5)], 1u << (m & 31));
        atomicOr(&adj[(size_t)(base + m) * NW + (n >> 5)], 1u << (n & 31));
    }
}

// ---------------------------------------------------------------------------
// Kernel 3: build weighted neighbor lists from adjacency bits.
__global__ void build_kernel(const float* __restrict__ feats,
                             const float4* __restrict__ centers4,
                             const float* __restrict__ invnorm,
                             const unsigned* __restrict__ adj,
                             int* __restrict__ nbr_idx,
                             float* __restrict__ nbr_w,
                             int* __restrict__ nbr_cnt,
                             const float* __restrict__ raw_sigma) {
    const int t = threadIdx.x;
    const int r = blockIdx.x;
    const int base = r - (r & (N - 1));

    __shared__ int    s_off[NW];
    __shared__ int    s_list[CAP];
    __shared__ float  s_w[CAP];
    __shared__ float4 s_fq[D / 4];
    __shared__ int    s_cnt;
    __shared__ float  s_sum;

    const float4* fq4 = reinterpret_cast<const float4*>(feats) + (size_t)r * (D / 4);
    if (t < D / 4) s_fq[t] = fq4[t];

    unsigned word = 0;
    if (t < NW) {
        word = adj[(size_t)r * NW + t];
        s_off[t] = __popc(word);
    }
    __syncthreads();
    if (t == 0) {
        int run = 0;
        for (int i = 0; i < NW; ++i) { int c = s_off[i]; s_off[i] = run; run += c; }
        s_cnt = run > CAP ? CAP : run;
    }
    __syncthreads();
    const int cnt = s_cnt;
    if (t < NW && word) {
        int o = s_off[t];
        unsigned w2 = word;
        while (w2) {
            int bit = __ffs(w2) - 1;
            if (o < CAP) s_list[o] = t * 32 + bit;
            ++o;
            w2 &= w2 - 1;
        }
    }
    __syncthreads();

    const float rs = raw_sigma[0];
    const float sigma = fmaxf(log1pf(expf(rs)), 1e-6f);
    const float nhalf_inv_s2 = -0.5f / (sigma * sigma);

    const int wid = t >> 6, lane = t & 63;
    const float inq = invnorm[r];
    const float4 cq = centers4[r];

    for (int i = wid; i < cnt; i += 4) {
        int m = s_list[i];
        int gm = base + m;
        float4 fm = reinterpret_cast<const float4*>(feats)[(size_t)gm * (D / 4) + lane];
        float4 fq = s_fq[lane];
        float p = fm.x * fq.x + fm.y * fq.y + fm.z * fq.z + fm.w * fq.w;
#pragma unroll
        for (int off = 32; off; off >>= 1) p += __shfl_xor(p, off);
        if (lane == 0) {
            float cosv = p * inq * invnorm[gm];
            float aff = fminf(fmaxf((cosv + 1.0f) * 0.5f, 0.0f), 1.0f);
            float4 cm = centers4[gm];
            float dist = fmaxf(cq.w + cm.w - 2.0f * (cq.x * cm.x + cq.y * cm.y + cq.z * cm.z), 0.0f);
            s_w[i] = expf(dist * nhalf_inv_s2) * aff;
        }
    }
    __syncthreads();
    if (t == 0) {
        float sum = 0.0f;
        for (int i = 0; i < cnt; ++i) sum += s_w[i];
        s_sum = fmaxf(sum, 1e-6f);
    }
    __syncthreads();
    for (int i = t; i < cnt; i += 256) {
        nbr_idx[(size_t)r * CAP + i] = s_list[i];
        nbr_w[(size_t)r * CAP + i]   = s_w[i] / s_sum;
    }
    if (t == 0) nbr_cnt[r] = cnt;
}

// ---------------------------------------------------------------------------
// Kernel 4: q = softmax(logits) rows. 32 lanes per row, 8 rows per block.
__global__ void softmax_kernel(const float* __restrict__ logits, float* __restrict__ q) {
    const int t = threadIdx.x;
    const int r = blockIdx.x * 8 + (t >> 5);
    const int c = t & 31;
    float x = logits[(size_t)r * C + c];
    float mx = x;
#pragma unroll
    for (int off = 16; off; off >>= 1) mx = fmaxf(mx, __shfl_xor(mx, off, 32));
    float e = expf(x - mx);
    float s = e;
#pragma unroll
    for (int off = 16; off; off >>= 1) s += __shfl_xor(s, off, 32);
    q[(size_t)r * C + c] = e / s;
}

// ---------------------------------------------------------------------------
// Kernel 5: one mean-field iteration. 32 lanes per row (class c per lane).
__global__ void iter_kernel(const float* __restrict__ logits,
                            const int* __restrict__ nbr_idx,
                            const float* __restrict__ nbr_w,
                            const int* __restrict__ nbr_cnt,
                            const float* __restrict__ q_in,
                            float* __restrict__ q_out,
                            float* __restrict__ refined_out,
                            const float* __restrict__ raw_smooth,
                            int write_refined) {
    const int t = threadIdx.x;
    const int r = blockIdx.x * 8 + (t >> 5);
    const int c = t & 31;
    const int base = r - (r & (N - 1));
    const float smooth = log1pf(expf(raw_smooth[0]));

    const int cnt = nbr_cnt[r];
    const int*   ip = nbr_idx + (size_t)r * CAP;
    const float* wp = nbr_w  + (size_t)r * CAP;

    float qn = 0.0f;
    for (int j = 0; j < cnt; ++j) {
        int m = ip[j];
        float w = wp[j];
        qn += w * q_in[(size_t)(base + m) * C + c];
    }

    const float fc = (float)c;
    float m0 = qn, m1 = qn * fc, m2 = qn * fc * fc;
#pragma unroll
    for (int off = 16; off; off >>= 1) {
        m0 += __shfl_xor(m0, off, 32);
        m1 += __shfl_xor(m1, off, 32);
        m2 += __shfl_xor(m2, off, 32);
    }
    float pw = (m2 - 2.0f * fc * m1 + fc * fc * m0) * (1.0f / 961.0f);
    float refined = logits[(size_t)r * C + c] - smooth * pw;
    if (write_refined) refined_out[(size_t)r * C + c] = refined;

    float mx = refined;
#pragma unroll
    for (int off = 16; off; off >>= 1) mx = fmaxf(mx, __shfl_xor(mx, off, 32));
    float e = expf(refined - mx);
    float s = e;
#pragma unroll
    for (int off = 16; off; off >>= 1) s += __shfl_xor(s, off, 32);
    q_out[(size_t)r * C + c] = e / s;
}

// ---------------------------------------------------------------------------
extern "C" void kernel_launch(void* const* d_in, const int* in_sizes, int n_in,
                              void* d_out, int out_size, void* d_ws, size_t ws_size,
                              hipStream_t stream) {
    const float* logits     = (const float*)d_in[0];
    const float* rois       = (const float*)d_in[1];
    const float* feats      = (const float*)d_in[2];
    const float* raw_sigma  = (const float*)d_in[3];
    const float* raw_smooth = (const float*)d_in[4];
    float* out = (float*)d_out;

    char* ws = (char*)d_ws;
    size_t off = 0;
    auto alloc = [&](size_t bytes) -> void* {
        void* p = ws + off;
        off += (bytes + 255) & ~(size_t)255;
        return p;
    };
    float4*   centers4 = (float4*)  alloc((size_t)ROWS * sizeof(float4));
    float*    invnorm  = (float*)   alloc((size_t)ROWS * 4);
    unsigned* adj      = (unsigned*)alloc((size_t)ROWS * NW * 4);
    int*      nbr_idx  = (int*)     alloc((size_t)ROWS * CAP * 4);
    float*    nbr_w    = (float*)   alloc((size_t)ROWS * CAP * 4);
    int*      nbr_cnt  = (int*)     alloc((size_t)ROWS * 4);
    float*    q_a      = (float*)   alloc((size_t)ROWS * C * 4);
    float*    q_b      = (float*)   alloc((size_t)ROWS * C * 4);

    hipMemsetAsync(adj, 0, (size_t)ROWS * NW * 4, stream);
    pre_kernel<<<ROWS / 4, 256, 0, stream>>>(rois, feats, centers4, invnorm);
    knn_kernel<<<ROWS / 16, 1024, 0, stream>>>(centers4, adj);
    build_kernel<<<ROWS, 256, 0, stream>>>(feats, centers4, invnorm, adj,
                                           nbr_idx, nbr_w, nbr_cnt, raw_sigma);
    softmax_kernel<<<ROWS / 8, 256, 0, stream>>>(logits, q_a);

    float* qi = q_a;
    float* qo = q_b;
    for (int it = 0; it < 5; ++it) {
        iter_kernel<<<ROWS / 8, 256, 0, stream>>>(logits, nbr_idx, nbr_w, nbr_cnt,
                                                  qi, qo, out, raw_smooth,
                                                  (it == 4) ? 1 : 0);
        float* tmp = qi; qi = qo; qo = tmp;
    }
}

// Round 5
// 130.494 us; speedup vs baseline: 2.2257x; 1.3233x over previous
//
#include <hip/hip_runtime.h>
#include <math.h>

// Problem constants (match reference setup_inputs)
constexpr int B = 2;
constexpr int N = 4096;
constexpr int C = 32;
constexpr int D = 256;
constexpr int K = 16;
constexpr int NW = N / 32;   // adjacency bitmask words per row = 128
constexpr int CAP = 128;     // max neighbors per row (16 out + in-degree)
constexpr int ROWS = B * N;  // 8192

// ---------------------------------------------------------------------------
// Kernel 1: per-row preprocess: centers(+sqnorm or INF if invalid), feature
// inv-norm. One wave (64 lanes) per row. Also zeroes the adjacency bitmask
// (grid covers ROWS*NW/2 uint2 exactly) so no separate memset dispatch.
__global__ void pre_kernel(const float* __restrict__ rois,
                           const float* __restrict__ feats,
                           float4* __restrict__ centers4,
                           float* __restrict__ invnorm,
                           uint2* __restrict__ adj_zero) {
    const int t = threadIdx.x;
    const int wid = t >> 6, lane = t & 63;
    const int r = blockIdx.x * 4 + wid;

    // zero adjacency: 2048 blocks * 256 threads == ROWS*NW/2 uint2 elements
    adj_zero[blockIdx.x * 256 + t] = make_uint2(0u, 0u);

    if (r >= ROWS) return;

    const float4* f4 = reinterpret_cast<const float4*>(feats) + (size_t)r * (D / 4);
    float4 v = f4[lane];
    float ss = v.x * v.x + v.y * v.y + v.z * v.z + v.w * v.w;
#pragma unroll
    for (int off = 32; off; off >>= 1) ss += __shfl_xor(ss, off);

    if (lane == 0) {
        invnorm[r] = 1.0f / fmaxf(sqrtf(ss), 1e-6f);
        const float* rp = rois + (size_t)r * 6;
        float a0 = rp[0], a1 = rp[1], a2 = rp[2], a3 = rp[3], a4 = rp[4], a5 = rp[5];
        float cx = (a0 + a3) * 0.5f, cy = (a1 + a4) * 0.5f, cz = (a2 + a5) * 0.5f;
        float sq = cx * cx + cy * cy + cz * cz;
        float s = fabsf(a0) + fabsf(a1) + fabsf(a2) + fabsf(a3) + fabsf(a4) + fabsf(a5);
        centers4[r] = make_float4(cx, cy, cz, (s > 0.0f) ? sq : INFINITY);
    }
}

// ---------------------------------------------------------------------------
// Kernel 2: brute-force 16-NN. 1024 threads = 16 rows (one wave each) share
// one 64KB AoS float4 LDS center table (ds_read_b128, conflict-free 16B/lane
// contiguous pattern) -> 2 blocks/CU, 8 waves/SIMD. Each lane owns 64
// candidates (m = lane + 64*j), keeps a top-3 in registers. Selection rounds
// reduce a 32-bit float dist (6 chained shfl), find the owner by ballot
// (unique-owner fast path; exact-tie path does an index-min reduce =>
// lax.top_k tie order). Lane exhaustion triggers a rare rescan gated by __any.
__global__ __launch_bounds__(1024, 8) void knn_kernel(const float4* __restrict__ centers4,
                                                      unsigned* __restrict__ adj) {
    __shared__ float4 s_c[N];   // 64 KB

    const int t = threadIdx.x;
    const int lane = t & 63;
    const int r = blockIdx.x * 16 + (t >> 6);
    const int n = r & (N - 1);
    const int base = r - n;

    for (int i = t; i < N; i += 1024) s_c[i] = centers4[base + i];
    __syncthreads();

    const float4 cq = s_c[n];
    const float cx = cq.x, cy = cq.y, cz = cq.z, cw = cq.w;

    // initial scan: per-lane top-3 (dist, j)
    float bd1 = INFINITY, bd2 = INFINITY, bd3 = INFINITY;
    int   bj1 = 0,        bj2 = 0,        bj3 = 0;
#pragma unroll 2
    for (int j = 0; j < 64; ++j) {
        const int m = lane + (j << 6);
        float4 cm = s_c[m];
        float dist = fmaxf(cw + cm.w - 2.0f * (cx * cm.x + cy * cm.y + cz * cm.z), 0.0f);
        dist = (m == n) ? INFINITY : dist;
        if (dist < bd1)      { bd3 = bd2; bj3 = bj2; bd2 = bd1; bj2 = bj1; bd1 = dist; bj1 = j; }
        else if (dist < bd2) { bd3 = bd2; bj3 = bj2; bd2 = dist; bj2 = j; }
        else if (dist < bd3) { bd3 = dist; bj3 = j; }
    }

    unsigned long long removed = 0ull;
    int my_sel = -1;

    for (int round = 0; round < K; ++round) {
        // wave-min of per-lane bd1 (32-bit chain)
        float md = bd1;
#pragma unroll
        for (int off = 32; off; off >>= 1) md = fminf(md, __shfl_xor(md, off));
        if (md == INFINITY) break;            // uniform: no finite candidates left

        unsigned long long tied = __ballot(bd1 == md);
        int wm;
        if (__popcll(tied) == 1) {            // unique owner (common case)
            int wl = __ffsll(tied) - 1;
            wm = __shfl((bj1 << 6) | lane, wl);
        } else {                              // exact tie: smallest index wins
            int kk = (bd1 == md) ? ((bj1 << 6) | lane) : 0x7FFFFFFF;
#pragma unroll
            for (int off = 32; off; off >>= 1) kk = min(kk, __shfl_xor(kk, off));
            wm = kk;
        }
        if (lane == round) my_sel = wm;

        if ((wm & 63) == lane) {              // this lane owned the winner
            removed |= 1ull << bj1;
            bd1 = bd2; bj1 = bj2;
            bd2 = bd3; bj2 = bj3;
            bd3 = INFINITY; bj3 = -1;         // marker: cache slot empty
        }
        const bool need = ((wm & 63) == lane) && (bj1 < 0);
        if (__any(need)) {
            if (need) {
                float nb1 = INFINITY, nb2 = INFINITY, nb3 = INFINITY;
                int   nj1 = 0,        nj2 = 0,        nj3 = 0;
#pragma unroll 2
                for (int j = 0; j < 64; ++j) {
                    const int m = lane + (j << 6);
                    float4 cm = s_c[m];
                    float dj = fmaxf(cw + cm.w - 2.0f * (cx * cm.x + cy * cm.y + cz * cm.z), 0.0f);
                    bool skip = ((removed >> j) & 1ull) || (m == n);
                    dj = skip ? INFINITY : dj;
                    if (dj < nb1)      { nb3 = nb2; nj3 = nj2; nb2 = nb1; nj2 = nj1; nb1 = dj; nj1 = j; }
                    else if (dj < nb2) { nb3 = nb2; nj3 = nj2; nb2 = dj; nj2 = j; }
                    else if (dj < nb3) { nb3 = dj; nj3 = j; }
                }
                bd1 = nb1; bj1 = nj1; bd2 = nb2; bj2 = nj2; bd3 = nb3; bj3 = nj3;
            }
        }
    }

    if (my_sel >= 0) {
        const int m = my_sel;
        atomicOr(&adj[(size_t)r * NW + (m >> 5)], 1u << (m & 31));
        atomicOr(&adj[(size_t)(base + m) * NW + (n >> 5)], 1u << (n & 31));
    }
}

// ---------------------------------------------------------------------------
// Kernel 3: build weighted neighbor lists from adjacency bits. One block per
// row. Parallel popcount-prefix (2-wave shfl_up scan), one wave per neighbor
// for the 256-d cosine dot, wave-parallel weight sum. Output interleaved
// (idx, w_bits) uint2 list.
__global__ void build_kernel(const float* __restrict__ feats,
                             const float4* __restrict__ centers4,
                             const float* __restrict__ invnorm,
                             const unsigned* __restrict__ adj,
                             uint2* __restrict__ nbr,
                             int* __restrict__ nbr_cnt,
                             const float* __restrict__ raw_sigma) {
    const int t = threadIdx.x;
    const int lane = t & 63;
    const int wv = t >> 6;
    const int r = blockIdx.x;
    const int base = r - (r & (N - 1));

    __shared__ int    s_off[NW];
    __shared__ int    s_wtot[2];
    __shared__ int    s_list[CAP];
    __shared__ float  s_w[CAP];
    __shared__ float4 s_fq[D / 4];
    __shared__ float  s_fsum[4];

    const float4* fq4 = reinterpret_cast<const float4*>(feats) + (size_t)r * (D / 4);
    if (t < D / 4) s_fq[t] = fq4[t];

    unsigned word = 0; int pc = 0;
    if (t < NW) {
        word = adj[(size_t)r * NW + t];
        pc = __popc(word);
    }
    // inclusive scan within each of the first two waves
    int sc = pc;
#pragma unroll
    for (int off = 1; off < 64; off <<= 1) {
        int o = __shfl_up(sc, off);
        if (lane >= off) sc += o;
    }
    if (t < NW && lane == 63) s_wtot[wv] = sc;
    __syncthreads();
    const int total = s_wtot[0] + s_wtot[1];
    const int cnt = total > CAP ? CAP : total;
    if (t < NW) s_off[t] = sc - pc + ((wv == 1) ? s_wtot[0] : 0);
    __syncthreads();

    if (t < NW && word) {
        int o = s_off[t];
        unsigned w2 = word;
        while (w2) {
            int bit = __ffs(w2) - 1;
            if (o < CAP) s_list[o] = t * 32 + bit;
            ++o;
            w2 &= w2 - 1;
        }
    }
    __syncthreads();

    const float rs = raw_sigma[0];
    const float sigma = fmaxf(log1pf(expf(rs)), 1e-6f);
    const float nhalf_inv_s2 = -0.5f / (sigma * sigma);

    const float inq = invnorm[r];
    const float4 cq = centers4[r];

    for (int i = wv; i < cnt; i += 4) {
        int m = s_list[i];
        int gm = base + m;
        float4 fm = reinterpret_cast<const float4*>(feats)[(size_t)gm * (D / 4) + lane];
        float4 fq = s_fq[lane];
        float p = fm.x * fq.x + fm.y * fq.y + fm.z * fq.z + fm.w * fq.w;
#pragma unroll
        for (int off = 32; off; off >>= 1) p += __shfl_xor(p, off);
        if (lane == 0) {
            float cosv = p * inq * invnorm[gm];
            float aff = fminf(fmaxf((cosv + 1.0f) * 0.5f, 0.0f), 1.0f);
            float4 cm = centers4[gm];
            float dist = fmaxf(cq.w + cm.w - 2.0f * (cq.x * cm.x + cq.y * cm.y + cq.z * cm.z), 0.0f);
            s_w[i] = expf(dist * nhalf_inv_s2) * aff;
        }
    }
    __syncthreads();

    // wave-parallel weight sum (deterministic)
    float ps = 0.0f;
    for (int i = t; i < cnt; i += 256) ps += s_w[i];
#pragma unroll
    for (int off = 32; off; off >>= 1) ps += __shfl_xor(ps, off);
    if (lane == 0) s_fsum[wv] = ps;
    __syncthreads();
    const float inv_sum = 1.0f / fmaxf(s_fsum[0] + s_fsum[1] + s_fsum[2] + s_fsum[3], 1e-6f);

    for (int i = t; i < cnt; i += 256) {
        nbr[(size_t)r * CAP + i] = make_uint2((unsigned)s_list[i],
                                              __float_as_uint(s_w[i] * inv_sum));
    }
    if (t == 0) nbr_cnt[r] = cnt;
}

// ---------------------------------------------------------------------------
// Kernel 4: q = softmax(logits) rows. 32 lanes per row, 8 rows per block.
__global__ void softmax_kernel(const float* __restrict__ logits, float* __restrict__ q) {
    const int t = threadIdx.x;
    const int r = blockIdx.x * 8 + (t >> 5);
    const int c = t & 31;
    float x = logits[(size_t)r * C + c];
    float mx = x;
#pragma unroll
    for (int off = 16; off; off >>= 1) mx = fmaxf(mx, __shfl_xor(mx, off, 32));
    float e = expf(x - mx);
    float s = e;
#pragma unroll
    for (int off = 16; off; off >>= 1) s += __shfl_xor(s, off, 32);
    q[(size_t)r * C + c] = e / s;
}

// ---------------------------------------------------------------------------
// Kernel 5: one mean-field iteration. 32 lanes per row (class c per lane).
__global__ void iter_kernel(const float* __restrict__ logits,
                            const uint2* __restrict__ nbr,
                            const int* __restrict__ nbr_cnt,
                            const float* __restrict__ q_in,
                            float* __restrict__ q_out,
                            float* __restrict__ refined_out,
                            const float* __restrict__ raw_smooth,
                            int write_refined) {
    const int t = threadIdx.x;
    const int r = blockIdx.x * 8 + (t >> 5);
    const int c = t & 31;
    const int base = r - (r & (N - 1));
    const float smooth = log1pf(expf(raw_smooth[0]));

    const int cnt = nbr_cnt[r];
    const uint2* np = nbr + (size_t)r * CAP;

    float qn = 0.0f;
#pragma unroll 4
    for (int j = 0; j < cnt; ++j) {
        uint2 e = np[j];
        qn += __uint_as_float(e.y) * q_in[(size_t)(base + (int)e.x) * C + c];
    }

    const float fc = (float)c;
    float m0 = qn, m1 = qn * fc, m2 = qn * fc * fc;
#pragma unroll
    for (int off = 16; off; off >>= 1) {
        m0 += __shfl_xor(m0, off, 32);
        m1 += __shfl_xor(m1, off, 32);
        m2 += __shfl_xor(m2, off, 32);
    }
    float pw = (m2 - 2.0f * fc * m1 + fc * fc * m0) * (1.0f / 961.0f);
    float refined = logits[(size_t)r * C + c] - smooth * pw;
    if (write_refined) refined_out[(size_t)r * C + c] = refined;

    float mx = refined;
#pragma unroll
    for (int off = 16; off; off >>= 1) mx = fmaxf(mx, __shfl_xor(mx, off, 32));
    float e = expf(refined - mx);
    float s = e;
#pragma unroll
    for (int off = 16; off; off >>= 1) s += __shfl_xor(s, off, 32);
    q_out[(size_t)r * C + c] = e / s;
}

// ---------------------------------------------------------------------------
extern "C" void kernel_launch(void* const* d_in, const int* in_sizes, int n_in,
                              void* d_out, int out_size, void* d_ws, size_t ws_size,
                              hipStream_t stream) {
    const float* logits     = (const float*)d_in[0];
    const float* rois       = (const float*)d_in[1];
    const float* feats      = (const float*)d_in[2];
    const float* raw_sigma  = (const float*)d_in[3];
    const float* raw_smooth = (const float*)d_in[4];
    float* out = (float*)d_out;

    char* ws = (char*)d_ws;
    size_t off = 0;
    auto alloc = [&](size_t bytes) -> void* {
        void* p = ws + off;
        off += (bytes + 255) & ~(size_t)255;
        return p;
    };
    float4*   centers4 = (float4*)  alloc((size_t)ROWS * sizeof(float4));
    float*    invnorm  = (float*)   alloc((size_t)ROWS * 4);
    unsigned* adj      = (unsigned*)alloc((size_t)ROWS * NW * 4);
    uint2*    nbr      = (uint2*)   alloc((size_t)ROWS * CAP * 8);
    int*      nbr_cnt  = (int*)     alloc((size_t)ROWS * 4);
    float*    q_a      = (float*)   alloc((size_t)ROWS * C * 4);
    float*    q_b      = (float*)   alloc((size_t)ROWS * C * 4);

    pre_kernel<<<ROWS / 4, 256, 0, stream>>>(rois, feats, centers4, invnorm, (uint2*)adj);
    knn_kernel<<<ROWS / 16, 1024, 0, stream>>>(centers4, adj);
    build_kernel<<<ROWS, 256, 0, stream>>>(feats, centers4, invnorm, adj,
                                           nbr, nbr_cnt, raw_sigma);
    softmax_kernel<<<ROWS / 8, 256, 0, stream>>>(logits, q_a);

    float* qi = q_a;
    float* qo = q_b;
    for (int it = 0; it < 5; ++it) {
        iter_kernel<<<ROWS / 8, 256, 0, stream>>>(logits, nbr, nbr_cnt,
                                                  qi, qo, out, raw_smooth,
                                                  (it == 4) ? 1 : 0);
        float* tmp = qi; qi = qo; qo = tmp;
    }
}

// Round 6
// 124.645 us; speedup vs baseline: 2.3301x; 1.0469x over previous
//
#include <hip/hip_runtime.h>
#include <math.h>

// Problem constants (match reference setup_inputs)
constexpr int B = 2;
constexpr int N = 4096;
constexpr int C = 32;
constexpr int D = 256;
constexpr int K = 16;
constexpr int NW = N / 32;   // adjacency bitmask words per row = 128
constexpr int CAP = 128;     // max neighbors per row (16 out + in-degree)
constexpr int ROWS = B * N;  // 8192

// ---------------------------------------------------------------------------
// Kernel 1: per-row preprocess: centers(+sqnorm or INF if invalid), feature
// inv-norm. One wave (64 lanes) per row. Also zeroes the adjacency bitmask
// (grid covers ROWS*NW/2 uint2 exactly) so no separate memset dispatch.
__global__ void pre_kernel(const float* __restrict__ rois,
                           const float* __restrict__ feats,
                           float4* __restrict__ centers4,
                           float* __restrict__ invnorm,
                           uint2* __restrict__ adj_zero) {
    const int t = threadIdx.x;
    const int wid = t >> 6, lane = t & 63;
    const int r = blockIdx.x * 4 + wid;

    // zero adjacency: 2048 blocks * 256 threads == ROWS*NW/2 uint2 elements
    adj_zero[blockIdx.x * 256 + t] = make_uint2(0u, 0u);

    if (r >= ROWS) return;

    const float4* f4 = reinterpret_cast<const float4*>(feats) + (size_t)r * (D / 4);
    float4 v = f4[lane];
    float ss = v.x * v.x + v.y * v.y + v.z * v.z + v.w * v.w;
#pragma unroll
    for (int off = 32; off; off >>= 1) ss += __shfl_xor(ss, off);

    if (lane == 0) {
        invnorm[r] = 1.0f / fmaxf(sqrtf(ss), 1e-6f);
        const float* rp = rois + (size_t)r * 6;
        float a0 = rp[0], a1 = rp[1], a2 = rp[2], a3 = rp[3], a4 = rp[4], a5 = rp[5];
        float cx = (a0 + a3) * 0.5f, cy = (a1 + a4) * 0.5f, cz = (a2 + a5) * 0.5f;
        float sq = cx * cx + cy * cy + cz * cz;
        float s = fabsf(a0) + fabsf(a1) + fabsf(a2) + fabsf(a3) + fabsf(a4) + fabsf(a5);
        centers4[r] = make_float4(cx, cy, cz, (s > 0.0f) ? sq : INFINITY);
    }
}

// ---------------------------------------------------------------------------
// Kernel 2: brute-force 16-NN. 1024 threads = 16 rows (one wave each) share
// one 64KB AoS float4 LDS center table -> 2 blocks/CU, 8 waves/SIMD.
// Scan is chunked by 8: 8 independent ds_read_b128 + dist computations are
// issued before the 8 sequential top-3 inserts (deep MLP, short dep chains).
// Selection rounds reduce a 32-bit float dist (6 chained shfl), find the
// owner by ballot (unique-owner fast path; exact-tie path does an index-min
// reduce => lax.top_k tie order). Lane exhaustion triggers a rare rescan.
__global__ __launch_bounds__(1024, 8) void knn_kernel(const float4* __restrict__ centers4,
                                                      unsigned* __restrict__ adj) {
    __shared__ float4 s_c[N];   // 64 KB

    const int t = threadIdx.x;
    const int lane = t & 63;
    const int r = blockIdx.x * 16 + (t >> 6);
    const int n = r & (N - 1);
    const int base = r - n;

    for (int i = t; i < N; i += 1024) s_c[i] = centers4[base + i];
    __syncthreads();

    const float4 cq = s_c[n];
    const float cx = cq.x, cy = cq.y, cz = cq.z, cw = cq.w;

    // initial scan: per-lane top-3 (dist, j), 8-wide load/compute batches
    float bd1 = INFINITY, bd2 = INFINITY, bd3 = INFINITY;
    int   bj1 = 0,        bj2 = 0,        bj3 = 0;
    for (int jb = 0; jb < 64; jb += 8) {
        float dd[8];
#pragma unroll
        for (int u = 0; u < 8; ++u) {
            const int m = lane + ((jb + u) << 6);
            float4 cm = s_c[m];
            float dist = fmaxf(cw + cm.w - 2.0f * (cx * cm.x + cy * cm.y + cz * cm.z), 0.0f);
            dd[u] = (m == n) ? INFINITY : dist;
        }
#pragma unroll
        for (int u = 0; u < 8; ++u) {
            const float dist = dd[u];
            const int j = jb + u;
            if (dist < bd1)      { bd3 = bd2; bj3 = bj2; bd2 = bd1; bj2 = bj1; bd1 = dist; bj1 = j; }
            else if (dist < bd2) { bd3 = bd2; bj3 = bj2; bd2 = dist; bj2 = j; }
            else if (dist < bd3) { bd3 = dist; bj3 = j; }
        }
    }

    unsigned long long removed = 0ull;
    int my_sel = -1;

    for (int round = 0; round < K; ++round) {
        // wave-min of per-lane bd1 (32-bit chain)
        float md = bd1;
#pragma unroll
        for (int off = 32; off; off >>= 1) md = fminf(md, __shfl_xor(md, off));
        if (md == INFINITY) break;            // uniform: no finite candidates left

        unsigned long long tied = __ballot(bd1 == md);
        int wm;
        if (__popcll(tied) == 1) {            // unique owner (common case)
            int wl = __ffsll(tied) - 1;
            wm = __shfl((bj1 << 6) | lane, wl);
        } else {                              // exact tie: smallest index wins
            int kk = (bd1 == md) ? ((bj1 << 6) | lane) : 0x7FFFFFFF;
#pragma unroll
            for (int off = 32; off; off >>= 1) kk = min(kk, __shfl_xor(kk, off));
            wm = kk;
        }
        if (lane == round) my_sel = wm;

        if ((wm & 63) == lane) {              // this lane owned the winner
            removed |= 1ull << bj1;
            bd1 = bd2; bj1 = bj2;
            bd2 = bd3; bj2 = bj3;
            bd3 = INFINITY; bj3 = -1;         // marker: cache slot empty
        }
        const bool need = ((wm & 63) == lane) && (bj1 < 0);
        if (__any(need)) {
            if (need) {
                float nb1 = INFINITY, nb2 = INFINITY, nb3 = INFINITY;
                int   nj1 = 0,        nj2 = 0,        nj3 = 0;
                for (int jb = 0; jb < 64; jb += 8) {
                    float dd[8];
#pragma unroll
                    for (int u = 0; u < 8; ++u) {
                        const int m = lane + ((jb + u) << 6);
                        float4 cm = s_c[m];
                        float dj = fmaxf(cw + cm.w - 2.0f * (cx * cm.x + cy * cm.y + cz * cm.z), 0.0f);
                        bool skip = ((removed >> (jb + u)) & 1ull) || (m == n);
                        dd[u] = skip ? INFINITY : dj;
                    }
#pragma unroll
                    for (int u = 0; u < 8; ++u) {
                        const float dj = dd[u];
                        const int j = jb + u;
                        if (dj < nb1)      { nb3 = nb2; nj3 = nj2; nb2 = nb1; nj2 = nj1; nb1 = dj; nj1 = j; }
                        else if (dj < nb2) { nb3 = nb2; nj3 = nj2; nb2 = dj; nj2 = j; }
                        else if (dj < nb3) { nb3 = dj; nj3 = j; }
                    }
                }
                bd1 = nb1; bj1 = nj1; bd2 = nb2; bj2 = nj2; bd3 = nb3; bj3 = nj3;
            }
        }
    }

    if (my_sel >= 0) {
        const int m = my_sel;
        atomicOr(&adj[(size_t)r * NW + (m >> 5)], 1u << (m & 31));
        atomicOr(&adj[(size_t)(base + m) * NW + (n >> 5)], 1u << (n & 31));
    }
}

// ---------------------------------------------------------------------------
// Kernel 3: build weighted neighbor lists from adjacency bits. One block per
// row. Parallel popcount-prefix (2-wave shfl_up scan), one wave per neighbor
// for the 256-d cosine dot, wave-parallel weight sum. Output interleaved
// (idx, w_bits) uint2 list. Fused: lanes <32 also compute q0 = softmax(logits)
// for this row at the end (saves a dispatch).
__global__ void build_kernel(const float* __restrict__ feats,
                             const float4* __restrict__ centers4,
                             const float* __restrict__ invnorm,
                             const unsigned* __restrict__ adj,
                             uint2* __restrict__ nbr,
                             int* __restrict__ nbr_cnt,
                             const float* __restrict__ raw_sigma,
                             const float* __restrict__ logits,
                             float* __restrict__ q0) {
    const int t = threadIdx.x;
    const int lane = t & 63;
    const int wv = t >> 6;
    const int r = blockIdx.x;
    const int base = r - (r & (N - 1));

    __shared__ int    s_off[NW];
    __shared__ int    s_wtot[2];
    __shared__ int    s_list[CAP];
    __shared__ float  s_w[CAP];
    __shared__ float4 s_fq[D / 4];
    __shared__ float  s_fsum[4];

    const float4* fq4 = reinterpret_cast<const float4*>(feats) + (size_t)r * (D / 4);
    if (t < D / 4) s_fq[t] = fq4[t];

    unsigned word = 0; int pc = 0;
    if (t < NW) {
        word = adj[(size_t)r * NW + t];
        pc = __popc(word);
    }
    // inclusive scan within each of the first two waves
    int sc = pc;
#pragma unroll
    for (int off = 1; off < 64; off <<= 1) {
        int o = __shfl_up(sc, off);
        if (lane >= off) sc += o;
    }
    if (t < NW && lane == 63) s_wtot[wv] = sc;
    __syncthreads();
    const int total = s_wtot[0] + s_wtot[1];
    const int cnt = total > CAP ? CAP : total;
    if (t < NW) s_off[t] = sc - pc + ((wv == 1) ? s_wtot[0] : 0);
    __syncthreads();

    if (t < NW && word) {
        int o = s_off[t];
        unsigned w2 = word;
        while (w2) {
            int bit = __ffs(w2) - 1;
            if (o < CAP) s_list[o] = t * 32 + bit;
            ++o;
            w2 &= w2 - 1;
        }
    }
    __syncthreads();

    const float rs = raw_sigma[0];
    const float sigma = fmaxf(log1pf(expf(rs)), 1e-6f);
    const float nhalf_inv_s2 = -0.5f / (sigma * sigma);

    const float inq = invnorm[r];
    const float4 cq = centers4[r];

    for (int i = wv; i < cnt; i += 4) {
        int m = s_list[i];
        int gm = base + m;
        float4 fm = reinterpret_cast<const float4*>(feats)[(size_t)gm * (D / 4) + lane];
        float4 fq = s_fq[lane];
        float p = fm.x * fq.x + fm.y * fq.y + fm.z * fq.z + fm.w * fq.w;
#pragma unroll
        for (int off = 32; off; off >>= 1) p += __shfl_xor(p, off);
        if (lane == 0) {
            float cosv = p * inq * invnorm[gm];
            float aff = fminf(fmaxf((cosv + 1.0f) * 0.5f, 0.0f), 1.0f);
            float4 cm = centers4[gm];
            float dist = fmaxf(cq.w + cm.w - 2.0f * (cq.x * cm.x + cq.y * cm.y + cq.z * cm.z), 0.0f);
            s_w[i] = expf(dist * nhalf_inv_s2) * aff;
        }
    }
    __syncthreads();

    // wave-parallel weight sum (deterministic)
    float ps = 0.0f;
    for (int i = t; i < cnt; i += 256) ps += s_w[i];
#pragma unroll
    for (int off = 32; off; off >>= 1) ps += __shfl_xor(ps, off);
    if (lane == 0) s_fsum[wv] = ps;
    __syncthreads();
    const float inv_sum = 1.0f / fmaxf(s_fsum[0] + s_fsum[1] + s_fsum[2] + s_fsum[3], 1e-6f);

    for (int i = t; i < cnt; i += 256) {
        nbr[(size_t)r * CAP + i] = make_uint2((unsigned)s_list[i],
                                              __float_as_uint(s_w[i] * inv_sum));
    }
    if (t == 0) nbr_cnt[r] = cnt;

    // fused initial softmax for this row (lanes 0..31)
    if (t < C) {
        float x = logits[(size_t)r * C + t];
        float mx = x;
#pragma unroll
        for (int off = 16; off; off >>= 1) mx = fmaxf(mx, __shfl_xor(mx, off, 32));
        float e = expf(x - mx);
        float s = e;
#pragma unroll
        for (int off = 16; off; off >>= 1) s += __shfl_xor(s, off, 32);
        q0[(size_t)r * C + t] = e / s;
    }
}

// ---------------------------------------------------------------------------
// Kernel 5: one mean-field iteration. 32 lanes per row (class c per lane).
__global__ void iter_kernel(const float* __restrict__ logits,
                            const uint2* __restrict__ nbr,
                            const int* __restrict__ nbr_cnt,
                            const float* __restrict__ q_in,
                            float* __restrict__ q_out,
                            float* __restrict__ refined_out,
                            const float* __restrict__ raw_smooth,
                            int write_refined) {
    const int t = threadIdx.x;
    const int r = blockIdx.x * 8 + (t >> 5);
    const int c = t & 31;
    const int base = r - (r & (N - 1));
    const float smooth = log1pf(expf(raw_smooth[0]));

    const int cnt = nbr_cnt[r];
    const uint2* np = nbr + (size_t)r * CAP;

    float qn = 0.0f;
#pragma unroll 4
    for (int j = 0; j < cnt; ++j) {
        uint2 e = np[j];
        qn += __uint_as_float(e.y) * q_in[(size_t)(base + (int)e.x) * C + c];
    }

    const float fc = (float)c;
    float m0 = qn, m1 = qn * fc, m2 = qn * fc * fc;
#pragma unroll
    for (int off = 16; off; off >>= 1) {
        m0 += __shfl_xor(m0, off, 32);
        m1 += __shfl_xor(m1, off, 32);
        m2 += __shfl_xor(m2, off, 32);
    }
    float pw = (m2 - 2.0f * fc * m1 + fc * fc * m0) * (1.0f / 961.0f);
    float refined = logits[(size_t)r * C + c] - smooth * pw;
    if (write_refined) refined_out[(size_t)r * C + c] = refined;

    float mx = refined;
#pragma unroll
    for (int off = 16; off; off >>= 1) mx = fmaxf(mx, __shfl_xor(mx, off, 32));
    float e = expf(refined - mx);
    float s = e;
#pragma unroll
    for (int off = 16; off; off >>= 1) s += __shfl_xor(s, off, 32);
    q_out[(size_t)r * C + c] = e / s;
}

// ---------------------------------------------------------------------------
extern "C" void kernel_launch(void* const* d_in, const int* in_sizes, int n_in,
                              void* d_out, int out_size, void* d_ws, size_t ws_size,
                              hipStream_t stream) {
    const float* logits     = (const float*)d_in[0];
    const float* rois       = (const float*)d_in[1];
    const float* feats      = (const float*)d_in[2];
    const float* raw_sigma  = (const float*)d_in[3];
    const float* raw_smooth = (const float*)d_in[4];
    float* out = (float*)d_out;

    char* ws = (char*)d_ws;
    size_t off = 0;
    auto alloc = [&](size_t bytes) -> void* {
        void* p = ws + off;
        off += (bytes + 255) & ~(size_t)255;
        return p;
    };
    float4*   centers4 = (float4*)  alloc((size_t)ROWS * sizeof(float4));
    float*    invnorm  = (float*)   alloc((size_t)ROWS * 4);
    unsigned* adj      = (unsigned*)alloc((size_t)ROWS * NW * 4);
    uint2*    nbr      = (uint2*)   alloc((size_t)ROWS * CAP * 8);
    int*      nbr_cnt  = (int*)     alloc((size_t)ROWS * 4);
    float*    q_a      = (float*)   alloc((size_t)ROWS * C * 4);
    float*    q_b      = (float*)   alloc((size_t)ROWS * C * 4);

    pre_kernel<<<ROWS / 4, 256, 0, stream>>>(rois, feats, centers4, invnorm, (uint2*)adj);
    knn_kernel<<<ROWS / 16, 1024, 0, stream>>>(centers4, adj);
    build_kernel<<<ROWS, 256, 0, stream>>>(feats, centers4, invnorm, adj,
                                           nbr, nbr_cnt, raw_sigma, logits, q_a);

    float* qi = q_a;
    float* qo = q_b;
    for (int it = 0; it < 5; ++it) {
        iter_kernel<<<ROWS / 8, 256, 0, stream>>>(logits, nbr, nbr_cnt,
                                                  qi, qo, out, raw_smooth,
                                                  (it == 4) ? 1 : 0);
        float* tmp = qi; qi = qo; qo = tmp;
    }
}

// Round 7
// 111.896 us; speedup vs baseline: 2.5956x; 1.1139x over previous
//
#include <hip/hip_runtime.h>
#include <math.h>

// Problem constants (match reference setup_inputs)
constexpr int B = 2;
constexpr int N = 4096;
constexpr int C = 32;
constexpr int D = 256;
constexpr int K = 16;
constexpr int NW = N / 32;   // adjacency bitmask words per row = 128
constexpr int CAP = 128;     // max neighbors per row (16 out + in-degree)
constexpr int ROWS = B * N;  // 8192

// ---------------------------------------------------------------------------
// Kernel 1: per-row preprocess: centers(+sqnorm or INF if invalid), feature
// inv-norm. One wave (64 lanes) per row. Also zeroes the adjacency bitmask
// (grid covers ROWS*NW/2 uint2 exactly) so no separate memset dispatch.
__global__ void pre_kernel(const float* __restrict__ rois,
                           const float* __restrict__ feats,
                           float4* __restrict__ centers4,
                           float* __restrict__ invnorm,
                           uint2* __restrict__ adj_zero) {
    const int t = threadIdx.x;
    const int wid = t >> 6, lane = t & 63;
    const int r = blockIdx.x * 4 + wid;

    // zero adjacency: 2048 blocks * 256 threads == ROWS*NW/2 uint2 elements
    adj_zero[blockIdx.x * 256 + t] = make_uint2(0u, 0u);

    if (r >= ROWS) return;

    const float4* f4 = reinterpret_cast<const float4*>(feats) + (size_t)r * (D / 4);
    float4 v = f4[lane];
    float ss = v.x * v.x + v.y * v.y + v.z * v.z + v.w * v.w;
#pragma unroll
    for (int off = 32; off; off >>= 1) ss += __shfl_xor(ss, off);

    if (lane == 0) {
        invnorm[r] = 1.0f / fmaxf(sqrtf(ss), 1e-6f);
        const float* rp = rois + (size_t)r * 6;
        float a0 = rp[0], a1 = rp[1], a2 = rp[2], a3 = rp[3], a4 = rp[4], a5 = rp[5];
        float cx = (a0 + a3) * 0.5f, cy = (a1 + a4) * 0.5f, cz = (a2 + a5) * 0.5f;
        float sq = cx * cx + cy * cy + cz * cz;
        float s = fabsf(a0) + fabsf(a1) + fabsf(a2) + fabsf(a3) + fabsf(a4) + fabsf(a5);
        centers4[r] = make_float4(cx, cy, cz, (s > 0.0f) ? sq : INFINITY);
    }
}

// ---------------------------------------------------------------------------
// Kernel 2: exact 16-NN via two-pass threshold select. 1024 thr = 16 rows
// (one wave each) share a 64KB AoS LDS center table (2 blocks/CU).
// Pass1: per-lane min over 64 candidates (min-only, no insert chain).
// tau = 16th-smallest of the 64 lane minima (bitonic value sort) — a provable
// upper bound on the true 16th-NN distance (subset argument). Pass2: collect
// candidates with dist <= tau (~20/row) into an LDS buffer as packed
// (dist_bits<<32|idx) keys. One u64 bitonic sort -> lanes 0..15 hold the
// exact lexicographic top-16 (ties -> smaller index, matching lax.top_k).
// Overflow (>64 survivors, e.g. invalid row => tau=INF) -> exact fallback.
__global__ __launch_bounds__(1024, 8) void knn_kernel(const float4* __restrict__ centers4,
                                                      unsigned* __restrict__ adj) {
    __shared__ float4 s_c[N];                        // 64 KB
    __shared__ unsigned long long s_buf[16][64];     // 8 KB survivor keys
    __shared__ int s_cnt[16];

    const int t = threadIdx.x;
    const int lane = t & 63;
    const int wv = t >> 6;
    const int r = blockIdx.x * 16 + wv;
    const int n = r & (N - 1);
    const int base = r - n;

    if (lane == 0) s_cnt[wv] = 0;
    for (int i = t; i < N; i += 1024) s_c[i] = centers4[base + i];
    __syncthreads();

    const float4 cq = s_c[n];
    const float cx = cq.x, cy = cq.y, cz = cq.z, cw = cq.w;

    // ---- pass 1: per-lane min distance (self excluded) ----
    float bmin = INFINITY;
    for (int j = 0; j < 64; ++j) {
        const int m = lane + (j << 6);
        float4 cm = s_c[m];
        float dist = fmaxf(cw + cm.w - 2.0f * (cx * cm.x + cy * cm.y + cz * cm.z), 0.0f);
        bmin = fminf(bmin, (m == n) ? INFINITY : dist);
    }

    // ---- bitonic sort of lane minima (values only, ascending) ----
    float v = bmin;
#pragma unroll
    for (int k = 2; k <= 64; k <<= 1) {
#pragma unroll
        for (int j = k >> 1; j > 0; j >>= 1) {
            float o = __shfl_xor(v, j);
            bool take_min = (((lane & j) == 0) == ((lane & k) == 0));
            v = take_min ? fminf(v, o) : fmaxf(v, o);
        }
    }
    const float tau = __shfl(v, 15);   // >= true d16

    // ---- pass 2: collect survivors into LDS ----
    for (int j = 0; j < 64; ++j) {
        const int m = lane + (j << 6);
        float4 cm = s_c[m];
        float dist = fmaxf(cw + cm.w - 2.0f * (cx * cm.x + cy * cm.y + cz * cm.z), 0.0f);
        if (dist <= tau && m != n) {
            int pos = atomicAdd(&s_cnt[wv], 1);
            if (pos < 64)
                s_buf[wv][pos] = ((unsigned long long)__float_as_uint(dist) << 32) | (unsigned)m;
        }
    }
    const int cnt = s_cnt[wv];   // wave-uniform (own wave's LDS ops complete in order)

    int my_sel = -1;
    if (cnt <= 64) {
        // ---- u64 bitonic sort of survivors; lanes 0..15 = exact top-16 ----
        unsigned long long key = (lane < cnt) ? s_buf[wv][lane] : ~0ull;
#pragma unroll
        for (int k = 2; k <= 64; k <<= 1) {
#pragma unroll
            for (int j = k >> 1; j > 0; j >>= 1) {
                unsigned long long o = __shfl_xor(key, j);
                bool take_min = (((lane & j) == 0) == ((lane & k) == 0));
                unsigned long long mn = (key < o) ? key : o;
                unsigned long long mx = (key < o) ? o : key;
                key = take_min ? mn : mx;
            }
        }
        if (lane < K && key != ~0ull) my_sel = (int)(unsigned)key;
    } else {
        // ---- exact fallback: 16 rounds of full rescan-argmin ----
        unsigned long long removed = 0ull;
        for (int round = 0; round < K; ++round) {
            float bd = INFINITY; int bi = 0x7FFFFFFF;
            for (int j = 0; j < 64; ++j) {
                const int m = lane + (j << 6);
                float4 cm = s_c[m];
                float dist = fmaxf(cw + cm.w - 2.0f * (cx * cm.x + cy * cm.y + cz * cm.z), 0.0f);
                bool skip = ((removed >> j) & 1ull) || (m == n);
                if (!skip && dist < bd) { bd = dist; bi = m; }
            }
            float md = bd;
#pragma unroll
            for (int off = 32; off; off >>= 1) md = fminf(md, __shfl_xor(md, off));
            if (md == INFINITY) break;
            int kk = (bd == md) ? bi : 0x7FFFFFFF;
#pragma unroll
            for (int off = 32; off; off >>= 1) kk = min(kk, __shfl_xor(kk, off));
            if (lane == round) my_sel = kk;
            if (kk == bi) removed |= 1ull << (bi >> 6);
        }
    }

    if (my_sel >= 0) {
        atomicOr(&adj[(size_t)r * NW + (my_sel >> 5)], 1u << (my_sel & 31));
        atomicOr(&adj[(size_t)(base + my_sel) * NW + (n >> 5)], 1u << (n & 31));
    }
}

// ---------------------------------------------------------------------------
// Kernel 3: build weighted neighbor lists from adjacency bits. One block per
// row. Parallel popcount-prefix (2-wave shfl_up scan), one wave per neighbor
// for the 256-d cosine dot, wave-parallel weight sum. Output interleaved
// (idx, w_bits) uint2 list. Fused: lanes <32 also compute q0 = softmax(logits)
// for this row at the end (saves a dispatch).
__global__ void build_kernel(const float* __restrict__ feats,
                             const float4* __restrict__ centers4,
                             const float* __restrict__ invnorm,
                             const unsigned* __restrict__ adj,
                             uint2* __restrict__ nbr,
                             int* __restrict__ nbr_cnt,
                             const float* __restrict__ raw_sigma,
                             const float* __restrict__ logits,
                             float* __restrict__ q0) {
    const int t = threadIdx.x;
    const int lane = t & 63;
    const int wv = t >> 6;
    const int r = blockIdx.x;
    const int base = r - (r & (N - 1));

    __shared__ int    s_off[NW];
    __shared__ int    s_wtot[2];
    __shared__ int    s_list[CAP];
    __shared__ float  s_w[CAP];
    __shared__ float4 s_fq[D / 4];
    __shared__ float  s_fsum[4];

    const float4* fq4 = reinterpret_cast<const float4*>(feats) + (size_t)r * (D / 4);
    if (t < D / 4) s_fq[t] = fq4[t];

    unsigned word = 0; int pc = 0;
    if (t < NW) {
        word = adj[(size_t)r * NW + t];
        pc = __popc(word);
    }
    // inclusive scan within each of the first two waves
    int sc = pc;
#pragma unroll
    for (int off = 1; off < 64; off <<= 1) {
        int o = __shfl_up(sc, off);
        if (lane >= off) sc += o;
    }
    if (t < NW && lane == 63) s_wtot[wv] = sc;
    __syncthreads();
    const int total = s_wtot[0] + s_wtot[1];
    const int cnt = total > CAP ? CAP : total;
    if (t < NW) s_off[t] = sc - pc + ((wv == 1) ? s_wtot[0] : 0);
    __syncthreads();

    if (t < NW && word) {
        int o = s_off[t];
        unsigned w2 = word;
        while (w2) {
            int bit = __ffs(w2) - 1;
            if (o < CAP) s_list[o] = t * 32 + bit;
            ++o;
            w2 &= w2 - 1;
        }
    }
    __syncthreads();

    const float rs = raw_sigma[0];
    const float sigma = fmaxf(log1pf(expf(rs)), 1e-6f);
    const float nhalf_inv_s2 = -0.5f / (sigma * sigma);

    const float inq = invnorm[r];
    const float4 cq = centers4[r];

    for (int i = wv; i < cnt; i += 4) {
        int m = s_list[i];
        int gm = base + m;
        float4 fm = reinterpret_cast<const float4*>(feats)[(size_t)gm * (D / 4) + lane];
        float4 fq = s_fq[lane];
        float p = fm.x * fq.x + fm.y * fq.y + fm.z * fq.z + fm.w * fq.w;
#pragma unroll
        for (int off = 32; off; off >>= 1) p += __shfl_xor(p, off);
        if (lane == 0) {
            float cosv = p * inq * invnorm[gm];
            float aff = fminf(fmaxf((cosv + 1.0f) * 0.5f, 0.0f), 1.0f);
            float4 cm = centers4[gm];
            float dist = fmaxf(cq.w + cm.w - 2.0f * (cq.x * cm.x + cq.y * cm.y + cq.z * cm.z), 0.0f);
            s_w[i] = expf(dist * nhalf_inv_s2) * aff;
        }
    }
    __syncthreads();

    // wave-parallel weight sum (deterministic)
    float ps = 0.0f;
    for (int i = t; i < cnt; i += 256) ps += s_w[i];
#pragma unroll
    for (int off = 32; off; off >>= 1) ps += __shfl_xor(ps, off);
    if (lane == 0) s_fsum[wv] = ps;
    __syncthreads();
    const float inv_sum = 1.0f / fmaxf(s_fsum[0] + s_fsum[1] + s_fsum[2] + s_fsum[3], 1e-6f);

    for (int i = t; i < cnt; i += 256) {
        nbr[(size_t)r * CAP + i] = make_uint2((unsigned)s_list[i],
                                              __float_as_uint(s_w[i] * inv_sum));
    }
    if (t == 0) nbr_cnt[r] = cnt;

    // fused initial softmax for this row (lanes 0..31)
    if (t < C) {
        float x = logits[(size_t)r * C + t];
        float mx = x;
#pragma unroll
        for (int off = 16; off; off >>= 1) mx = fmaxf(mx, __shfl_xor(mx, off, 32));
        float e = expf(x - mx);
        float s = e;
#pragma unroll
        for (int off = 16; off; off >>= 1) s += __shfl_xor(s, off, 32);
        q0[(size_t)r * C + t] = e / s;
    }
}

// ---------------------------------------------------------------------------
// Kernel 5: one mean-field iteration. 32 lanes per row (class c per lane).
__global__ void iter_kernel(const float* __restrict__ logits,
                            const uint2* __restrict__ nbr,
                            const int* __restrict__ nbr_cnt,
                            const float* __restrict__ q_in,
                            float* __restrict__ q_out,
                            float* __restrict__ refined_out,
                            const float* __restrict__ raw_smooth,
                            int write_refined) {
    const int t = threadIdx.x;
    const int r = blockIdx.x * 8 + (t >> 5);
    const int c = t & 31;
    const int base = r - (r & (N - 1));
    const float smooth = log1pf(expf(raw_smooth[0]));

    const int cnt = nbr_cnt[r];
    const uint2* np = nbr + (size_t)r * CAP;

    float qn = 0.0f;
#pragma unroll 4
    for (int j = 0; j < cnt; ++j) {
        uint2 e = np[j];
        qn += __uint_as_float(e.y) * q_in[(size_t)(base + (int)e.x) * C + c];
    }

    const float fc = (float)c;
    float m0 = qn, m1 = qn * fc, m2 = qn * fc * fc;
#pragma unroll
    for (int off = 16; off; off >>= 1) {
        m0 += __shfl_xor(m0, off, 32);
        m1 += __shfl_xor(m1, off, 32);
        m2 += __shfl_xor(m2, off, 32);
    }
    float pw = (m2 - 2.0f * fc * m1 + fc * fc * m0) * (1.0f / 961.0f);
    float refined = logits[(size_t)r * C + c] - smooth * pw;
    if (write_refined) refined_out[(size_t)r * C + c] = refined;

    float mx = refined;
#pragma unroll
    for (int off = 16; off; off >>= 1) mx = fmaxf(mx, __shfl_xor(mx, off, 32));
    float e = expf(refined - mx);
    float s = e;
#pragma unroll
    for (int off = 16; off; off >>= 1) s += __shfl_xor(s, off, 32);
    q_out[(size_t)r * C + c] = e / s;
}

// ---------------------------------------------------------------------------
extern "C" void kernel_launch(void* const* d_in, const int* in_sizes, int n_in,
                              void* d_out, int out_size, void* d_ws, size_t ws_size,
                              hipStream_t stream) {
    const float* logits     = (const float*)d_in[0];
    const float* rois       = (const float*)d_in[1];
    const float* feats      = (const float*)d_in[2];
    const float* raw_sigma  = (const float*)d_in[3];
    const float* raw_smooth = (const float*)d_in[4];
    float* out = (float*)d_out;

    char* ws = (char*)d_ws;
    size_t off = 0;
    auto alloc = [&](size_t bytes) -> void* {
        void* p = ws + off;
        off += (bytes + 255) & ~(size_t)255;
        return p;
    };
    float4*   centers4 = (float4*)  alloc((size_t)ROWS * sizeof(float4));
    float*    invnorm  = (float*)   alloc((size_t)ROWS * 4);
    unsigned* adj      = (unsigned*)alloc((size_t)ROWS * NW * 4);
    uint2*    nbr      = (uint2*)   alloc((size_t)ROWS * CAP * 8);
    int*      nbr_cnt  = (int*)     alloc((size_t)ROWS * 4);
    float*    q_a      = (float*)   alloc((size_t)ROWS * C * 4);
    float*    q_b      = (float*)   alloc((size_t)ROWS * C * 4);

    pre_kernel<<<ROWS / 4, 256, 0, stream>>>(rois, feats, centers4, invnorm, (uint2*)adj);
    knn_kernel<<<ROWS / 16, 1024, 0, stream>>>(centers4, adj);
    build_kernel<<<ROWS, 256, 0, stream>>>(feats, centers4, invnorm, adj,
                                           nbr, nbr_cnt, raw_sigma, logits, q_a);

    float* qi = q_a;
    float* qo = q_b;
    for (int it = 0; it < 5; ++it) {
        iter_kernel<<<ROWS / 8, 256, 0, stream>>>(logits, nbr, nbr_cnt,
                                                  qi, qo, out, raw_smooth,
                                                  (it == 4) ? 1 : 0);
        float* tmp = qi; qi = qo; qo = tmp;
    }
}

// Round 9
// 107.737 us; speedup vs baseline: 2.6958x; 1.0386x over previous
//
#include <hip/hip_runtime.h>
#include <math.h>

// Problem constants (match reference setup_inputs)
constexpr int B = 2;
constexpr int N = 4096;
constexpr int C = 32;
constexpr int D = 256;
constexpr int K = 16;
constexpr int NW = N / 32;   // adjacency bitmask words per row = 128
constexpr int CAP = 128;     // max neighbors per row (16 out + in-degree)
constexpr int ROWS = B * N;  // 8192

// ---------------------------------------------------------------------------
// Kernel 1: per-row preprocess: centers(+sqnorm or INF if invalid), feature
// inv-norm. One wave (64 lanes) per row. Also zeroes the adjacency bitmask.
__global__ void pre_kernel(const float* __restrict__ rois,
                           const float* __restrict__ feats,
                           float4* __restrict__ centers4,
                           float* __restrict__ invnorm,
                           uint2* __restrict__ adj_zero) {
    const int t = threadIdx.x;
    const int wid = t >> 6, lane = t & 63;
    const int r = blockIdx.x * 4 + wid;

    // zero adjacency: 2048 blocks * 256 threads == ROWS*NW/2 uint2 elements
    adj_zero[blockIdx.x * 256 + t] = make_uint2(0u, 0u);

    if (r >= ROWS) return;

    const float4* f4 = reinterpret_cast<const float4*>(feats) + (size_t)r * (D / 4);
    float4 v = f4[lane];
    float ss = v.x * v.x + v.y * v.y + v.z * v.z + v.w * v.w;
#pragma unroll
    for (int off = 32; off; off >>= 1) ss += __shfl_xor(ss, off);

    if (lane == 0) {
        invnorm[r] = 1.0f / fmaxf(sqrtf(ss), 1e-6f);
        const float* rp = rois + (size_t)r * 6;
        float a0 = rp[0], a1 = rp[1], a2 = rp[2], a3 = rp[3], a4 = rp[4], a5 = rp[5];
        float cx = (a0 + a3) * 0.5f, cy = (a1 + a4) * 0.5f, cz = (a2 + a5) * 0.5f;
        float sq = cx * cx + cy * cy + cz * cz;
        float s = fabsf(a0) + fabsf(a1) + fabsf(a2) + fabsf(a3) + fabsf(a4) + fabsf(a5);
        centers4[r] = make_float4(cx, cy, cz, (s > 0.0f) ? sq : INFINITY);
    }
}

// ---------------------------------------------------------------------------
// Kernel 2: exact 16-NN, chunk-in-register restructure.
// 1024 thr = 16 waves; block covers 16 rows of one batch. Each wave owns a
// 256-candidate chunk in REGISTERS (4 float4/lane, loaded from LDS once) and
// evaluates it against ALL 16 row centers (LDS broadcasts): ds_read_b128
// traffic drops 16x vs wave-per-row scanning. Per-(row,lane-subset) minima
// combined across waves via LDS atomicMin on float bits (dists >= 0).
// tau[row] = 16th smallest of the 64 subset minima (bitonic sort) — provable
// upper bound on true d16 (subset argument, same subsets as R6/R7).
// Pass 2 appends survivors (dist<=tau) as (dist_bits<<32|idx) u64 keys; the
// per-row u64 bitonic sort canonicalizes append order -> exact deterministic
// top-16, ties to smaller index (matches lax.top_k). Overflow (>64) or
// invalid rows (tau=INF) -> per-wave exact fallback.
__global__ __launch_bounds__(1024, 8) void knn_kernel(const float4* __restrict__ centers4,
                                                      unsigned* __restrict__ adj) {
    __shared__ float4 s_c[N];                        // 64 KB
    __shared__ unsigned s_pm[16][64];                // 4 KB subset-min bits
    __shared__ unsigned long long s_buf[16][64];     // 8 KB survivor keys
    __shared__ int s_cnt[16];
    __shared__ float s_tau[16];

    const int t = threadIdx.x;
    const int lane = t & 63;
    const int wv = t >> 6;
    const int r0 = blockIdx.x * 16;        // first global row of block
    const int nbase = r0 & (N - 1);        // first in-batch row index
    const int gbase = r0 - nbase;          // batch offset (0 or N)

    if (t < 16) s_cnt[t] = 0;
    ((unsigned*)s_pm)[t] = 0x7F800000u;    // +INF bits (1024 entries exactly)
    for (int i = t; i < N; i += 1024) s_c[i] = centers4[gbase + i];
    __syncthreads();

    // wave-owned candidate chunk, kept in registers
    float4 cmv[4];
    int    mv[4];
#pragma unroll
    for (int u = 0; u < 4; ++u) {
        mv[u] = (wv << 8) + (u << 6) + lane;
        cmv[u] = s_c[mv[u]];
    }

    // ---- pass 1: per-row min over this lane's 4 candidates; merge via atomicMin ----
#pragma unroll 4
    for (int rr = 0; rr < 16; ++rr) {
        const int nrow = nbase + rr;
        const float4 rc = s_c[nrow];       // same-address broadcast, conflict-free
        float mn = INFINITY;
#pragma unroll
        for (int u = 0; u < 4; ++u) {
            float dist = fmaxf(rc.w + cmv[u].w -
                               2.0f * (rc.x * cmv[u].x + rc.y * cmv[u].y + rc.z * cmv[u].z), 0.0f);
            mn = fminf(mn, (mv[u] == nrow) ? INFINITY : dist);
        }
        atomicMin(&s_pm[rr][lane], __float_as_uint(mn));
    }
    __syncthreads();

    // ---- tau per row: wave rr sorts its row's 64 subset minima ----
    {
        float v = __uint_as_float(s_pm[wv][lane]);
#pragma unroll
        for (int k = 2; k <= 64; k <<= 1) {
#pragma unroll
            for (int j = k >> 1; j > 0; j >>= 1) {
                float o = __shfl_xor(v, j);
                bool take_min = (((lane & j) == 0) == ((lane & k) == 0));
                v = take_min ? fminf(v, o) : fmaxf(v, o);
            }
        }
        if (lane == 15) s_tau[wv] = v;     // 16th smallest
    }
    __syncthreads();

    // ---- pass 2: append survivors from the register chunk for all 16 rows ----
#pragma unroll 4
    for (int rr = 0; rr < 16; ++rr) {
        const int nrow = nbase + rr;
        const float tau = s_tau[rr];
        const float4 rc = s_c[nrow];
#pragma unroll
        for (int u = 0; u < 4; ++u) {
            float dist = fmaxf(rc.w + cmv[u].w -
                               2.0f * (rc.x * cmv[u].x + rc.y * cmv[u].y + rc.z * cmv[u].z), 0.0f);
            if (dist <= tau && mv[u] != nrow) {
                int pos = atomicAdd(&s_cnt[rr], 1);
                if (pos < 64)
                    s_buf[rr][pos] = ((unsigned long long)__float_as_uint(dist) << 32)
                                     | (unsigned)mv[u];
            }
        }
    }
    __syncthreads();

    // ---- selection: wave rr owns row rr ----
    const int rg = r0 + wv;                // global row
    const int n = nbase + wv;              // in-batch row
    const int cnt = s_cnt[wv];

    int my_sel = -1;
    if (cnt <= 64) {
        unsigned long long key = (lane < cnt) ? s_buf[wv][lane] : ~0ull;
#pragma unroll
        for (int k = 2; k <= 64; k <<= 1) {
#pragma unroll
            for (int j = k >> 1; j > 0; j >>= 1) {
                unsigned long long o = __shfl_xor(key, j);
                bool take_min = (((lane & j) == 0) == ((lane & k) == 0));
                unsigned long long mn = (key < o) ? key : o;
                unsigned long long mx = (key < o) ? o : key;
                key = take_min ? mn : mx;
            }
        }
        if (lane < K && key != ~0ull) my_sel = (int)(unsigned)key;
    } else {
        // exact fallback: 16 rounds of full rescan-argmin over LDS table
        const float4 cq = s_c[n];
        unsigned long long removed = 0ull;
        for (int round = 0; round < K; ++round) {
            float bd = INFINITY; int bi = 0x7FFFFFFF;
            for (int j = 0; j < 64; ++j) {
                const int m = lane + (j << 6);
                float4 cm = s_c[m];
                float dist = fmaxf(cq.w + cm.w -
                                   2.0f * (cq.x * cm.x + cq.y * cm.y + cq.z * cm.z), 0.0f);
                bool skip = ((removed >> j) & 1ull) || (m == n);
                if (!skip && dist < bd) { bd = dist; bi = m; }
            }
            float md = bd;
#pragma unroll
            for (int off = 32; off; off >>= 1) md = fminf(md, __shfl_xor(md, off));
            if (md == INFINITY) break;
            int kk = (bd == md) ? bi : 0x7FFFFFFF;
#pragma unroll
            for (int off = 32; off; off >>= 1) kk = min(kk, __shfl_xor(kk, off));
            if (lane == round) my_sel = kk;
            if (kk == bi) removed |= 1ull << (bi >> 6);
        }
    }

    if (my_sel >= 0) {
        atomicOr(&adj[(size_t)rg * NW + (my_sel >> 5)], 1u << (my_sel & 31));
        atomicOr(&adj[(size_t)(gbase + my_sel) * NW + (n >> 5)], 1u << (n & 31));
    }
}

// ---------------------------------------------------------------------------
// Kernel 3: build weighted neighbor lists from adjacency bits. One block per
// row. Parallel popcount-prefix, one wave per neighbor for the 256-d cosine
// dot, wave-parallel weight sum. Fused: lanes <32 compute q0 = softmax(logits).
__global__ void build_kernel(const float* __restrict__ feats,
                             const float4* __restrict__ centers4,
                             const float* __restrict__ invnorm,
                             const unsigned* __restrict__ adj,
                             uint2* __restrict__ nbr,
                             int* __restrict__ nbr_cnt,
                             const float* __restrict__ raw_sigma,
                             const float* __restrict__ logits,
                             float* __restrict__ q0) {
    const int t = threadIdx.x;
    const int lane = t & 63;
    const int wv = t >> 6;
    const int r = blockIdx.x;
    const int base = r - (r & (N - 1));

    __shared__ int    s_off[NW];
    __shared__ int    s_wtot[2];
    __shared__ int    s_list[CAP];
    __shared__ float  s_w[CAP];
    __shared__ float4 s_fq[D / 4];
    __shared__ float  s_fsum[4];

    const float4* fq4 = reinterpret_cast<const float4*>(feats) + (size_t)r * (D / 4);
    if (t < D / 4) s_fq[t] = fq4[t];

    unsigned word = 0; int pc = 0;
    if (t < NW) {
        word = adj[(size_t)r * NW + t];
        pc = __popc(word);
    }
    int sc = pc;
#pragma unroll
    for (int off = 1; off < 64; off <<= 1) {
        int o = __shfl_up(sc, off);
        if (lane >= off) sc += o;
    }
    if (t < NW && lane == 63) s_wtot[wv] = sc;
    __syncthreads();
    const int total = s_wtot[0] + s_wtot[1];
    const int cnt = total > CAP ? CAP : total;
    if (t < NW) s_off[t] = sc - pc + ((wv == 1) ? s_wtot[0] : 0);
    __syncthreads();

    if (t < NW && word) {
        int o = s_off[t];
        unsigned w2 = word;
        while (w2) {
            int bit = __ffs(w2) - 1;
            if (o < CAP) s_list[o] = t * 32 + bit;
            ++o;
            w2 &= w2 - 1;
        }
    }
    __syncthreads();

    const float rs = raw_sigma[0];
    const float sigma = fmaxf(log1pf(expf(rs)), 1e-6f);
    const float nhalf_inv_s2 = -0.5f / (sigma * sigma);

    const float inq = invnorm[r];
    const float4 cq = centers4[r];

    for (int i = wv; i < cnt; i += 4) {
        int m = s_list[i];
        int gm = base + m;
        float4 fm = reinterpret_cast<const float4*>(feats)[(size_t)gm * (D / 4) + lane];
        float4 fq = s_fq[lane];
        float p = fm.x * fq.x + fm.y * fq.y + fm.z * fq.z + fm.w * fq.w;
#pragma unroll
        for (int off = 32; off; off >>= 1) p += __shfl_xor(p, off);
        if (lane == 0) {
            float cosv = p * inq * invnorm[gm];
            float aff = fminf(fmaxf((cosv + 1.0f) * 0.5f, 0.0f), 1.0f);
            float4 cm = centers4[gm];
            float dist = fmaxf(cq.w + cm.w - 2.0f * (cq.x * cm.x + cq.y * cm.y + cq.z * cm.z), 0.0f);
            s_w[i] = expf(dist * nhalf_inv_s2) * aff;
        }
    }
    __syncthreads();

    float ps = 0.0f;
    for (int i = t; i < cnt; i += 256) ps += s_w[i];
#pragma unroll
    for (int off = 32; off; off >>= 1) ps += __shfl_xor(ps, off);
    if (lane == 0) s_fsum[wv] = ps;
    __syncthreads();
    const float inv_sum = 1.0f / fmaxf(s_fsum[0] + s_fsum[1] + s_fsum[2] + s_fsum[3], 1e-6f);

    for (int i = t; i < cnt; i += 256) {
        nbr[(size_t)r * CAP + i] = make_uint2((unsigned)s_list[i],
                                              __float_as_uint(s_w[i] * inv_sum));
    }
    if (t == 0) nbr_cnt[r] = cnt;

    if (t < C) {
        float x = logits[(size_t)r * C + t];
        float mx = x;
#pragma unroll
        for (int off = 16; off; off >>= 1) mx = fmaxf(mx, __shfl_xor(mx, off, 32));
        float e = expf(x - mx);
        float s = e;
#pragma unroll
        for (int off = 16; off; off >>= 1) s += __shfl_xor(s, off, 32);
        q0[(size_t)r * C + t] = e / s;
    }
}

// ---------------------------------------------------------------------------
// Kernel 4: one mean-field iteration. 32 lanes per row (class c per lane).
// (Separate stream-ordered launches; cooperative grid.sync does NOT survive
//  graph capture on this harness — R8 post-mortem.)
__global__ void iter_kernel(const float* __restrict__ logits,
                            const uint2* __restrict__ nbr,
                            const int* __restrict__ nbr_cnt,
                            const float* __restrict__ q_in,
                            float* __restrict__ q_out,
                            float* __restrict__ refined_out,
                            const float* __restrict__ raw_smooth,
                            int write_refined) {
    const int t = threadIdx.x;
    const int r = blockIdx.x * 8 + (t >> 5);
    const int c = t & 31;
    const int base = r - (r & (N - 1));
    const float smooth = log1pf(expf(raw_smooth[0]));

    const int cnt = nbr_cnt[r];
    const uint2* np = nbr + (size_t)r * CAP;

    float qn = 0.0f;
#pragma unroll 4
    for (int j = 0; j < cnt; ++j) {
        uint2 e = np[j];
        qn += __uint_as_float(e.y) * q_in[(size_t)(base + (int)e.x) * C + c];
    }

    const float fc = (float)c;
    float m0 = qn, m1 = qn * fc, m2 = qn * fc * fc;
#pragma unroll
    for (int off = 16; off; off >>= 1) {
        m0 += __shfl_xor(m0, off, 32);
        m1 += __shfl_xor(m1, off, 32);
        m2 += __shfl_xor(m2, off, 32);
    }
    float pw = (m2 - 2.0f * fc * m1 + fc * fc * m0) * (1.0f / 961.0f);
    float refined = logits[(size_t)r * C + c] - smooth * pw;
    if (write_refined) refined_out[(size_t)r * C + c] = refined;

    float mx = refined;
#pragma unroll
    for (int off = 16; off; off >>= 1) mx = fmaxf(mx, __shfl_xor(mx, off, 32));
    float e = expf(refined - mx);
    float s = e;
#pragma unroll
    for (int off = 16; off; off >>= 1) s += __shfl_xor(s, off, 32);
    q_out[(size_t)r * C + c] = e / s;
}

// ---------------------------------------------------------------------------
extern "C" void kernel_launch(void* const* d_in, const int* in_sizes, int n_in,
                              void* d_out, int out_size, void* d_ws, size_t ws_size,
                              hipStream_t stream) {
    const float* logits     = (const float*)d_in[0];
    const float* rois       = (const float*)d_in[1];
    const float* feats      = (const float*)d_in[2];
    const float* raw_sigma  = (const float*)d_in[3];
    const float* raw_smooth = (const float*)d_in[4];
    float* out = (float*)d_out;

    char* ws = (char*)d_ws;
    size_t off = 0;
    auto alloc = [&](size_t bytes) -> void* {
        void* p = ws + off;
        off += (bytes + 255) & ~(size_t)255;
        return p;
    };
    float4*   centers4 = (float4*)  alloc((size_t)ROWS * sizeof(float4));
    float*    invnorm  = (float*)   alloc((size_t)ROWS * 4);
    unsigned* adj      = (unsigned*)alloc((size_t)ROWS * NW * 4);
    uint2*    nbr      = (uint2*)   alloc((size_t)ROWS * CAP * 8);
    int*      nbr_cnt  = (int*)     alloc((size_t)ROWS * 4);
    float*    q_a      = (float*)   alloc((size_t)ROWS * C * 4);
    float*    q_b      = (float*)   alloc((size_t)ROWS * C * 4);

    pre_kernel<<<ROWS / 4, 256, 0, stream>>>(rois, feats, centers4, invnorm, (uint2*)adj);
    knn_kernel<<<ROWS / 16, 1024, 0, stream>>>(centers4, adj);
    build_kernel<<<ROWS, 256, 0, stream>>>(feats, centers4, invnorm, adj,
                                           nbr, nbr_cnt, raw_sigma, logits, q_a);

    float* qi = q_a;
    float* qo = q_b;
    for (int it = 0; it < 5; ++it) {
        iter_kernel<<<ROWS / 8, 256, 0, stream>>>(logits, nbr, nbr_cnt,
                                                  qi, qo, out, raw_smooth,
                                                  (it == 4) ? 1 : 0);
        float* tmp = qi; qi = qo; qo = tmp;
    }
}

// Round 10
// 90.021 us; speedup vs baseline: 3.2264x; 1.1968x over previous
//
#include <hip/hip_runtime.h>
#include <math.h>

// Problem constants (match reference setup_inputs)
constexpr int B = 2;
constexpr int N = 4096;
constexpr int C = 32;
constexpr int D = 256;
constexpr int K = 16;
constexpr int NW = N / 32;   // adjacency bitmask words per row = 128
constexpr int CAP = 128;     // max neighbors per row (16 out + in-degree)
constexpr int ROWS = B * N;  // 8192

// ---------------------------------------------------------------------------
// Kernel 1: per-row preprocess: centers(+sqnorm or INF if invalid), feature
// inv-norm. One wave (64 lanes) per row. Also zeroes the adjacency bitmask.
__global__ void pre_kernel(const float* __restrict__ rois,
                           const float* __restrict__ feats,
                           float4* __restrict__ centers4,
                           float* __restrict__ invnorm,
                           uint2* __restrict__ adj_zero) {
    const int t = threadIdx.x;
    const int wid = t >> 6, lane = t & 63;
    const int r = blockIdx.x * 4 + wid;

    // zero adjacency: 2048 blocks * 256 threads == ROWS*NW/2 uint2 elements
    adj_zero[blockIdx.x * 256 + t] = make_uint2(0u, 0u);

    if (r >= ROWS) return;

    const float4* f4 = reinterpret_cast<const float4*>(feats) + (size_t)r * (D / 4);
    float4 v = f4[lane];
    float ss = v.x * v.x + v.y * v.y + v.z * v.z + v.w * v.w;
#pragma unroll
    for (int off = 32; off; off >>= 1) ss += __shfl_xor(ss, off);

    if (lane == 0) {
        invnorm[r] = 1.0f / fmaxf(sqrtf(ss), 1e-6f);
        const float* rp = rois + (size_t)r * 6;
        float a0 = rp[0], a1 = rp[1], a2 = rp[2], a3 = rp[3], a4 = rp[4], a5 = rp[5];
        float cx = (a0 + a3) * 0.5f, cy = (a1 + a4) * 0.5f, cz = (a2 + a5) * 0.5f;
        float sq = cx * cx + cy * cy + cz * cz;
        float s = fabsf(a0) + fabsf(a1) + fabsf(a2) + fabsf(a3) + fabsf(a4) + fabsf(a5);
        centers4[r] = make_float4(cx, cy, cz, (s > 0.0f) ? sq : INFINITY);
    }
}

// ---------------------------------------------------------------------------
// Kernel 2: exact 16-NN, chunk-in-register structure (see R8 notes).
__global__ __launch_bounds__(1024, 8) void knn_kernel(const float4* __restrict__ centers4,
                                                      unsigned* __restrict__ adj) {
    __shared__ float4 s_c[N];                        // 64 KB
    __shared__ unsigned s_pm[16][64];                // 4 KB subset-min bits
    __shared__ unsigned long long s_buf[16][64];     // 8 KB survivor keys
    __shared__ int s_cnt[16];
    __shared__ float s_tau[16];

    const int t = threadIdx.x;
    const int lane = t & 63;
    const int wv = t >> 6;
    const int r0 = blockIdx.x * 16;        // first global row of block
    const int nbase = r0 & (N - 1);        // first in-batch row index
    const int gbase = r0 - nbase;          // batch offset (0 or N)

    if (t < 16) s_cnt[t] = 0;
    ((unsigned*)s_pm)[t] = 0x7F800000u;    // +INF bits (1024 entries exactly)
    for (int i = t; i < N; i += 1024) s_c[i] = centers4[gbase + i];
    __syncthreads();

    // wave-owned candidate chunk, kept in registers
    float4 cmv[4];
    int    mv[4];
#pragma unroll
    for (int u = 0; u < 4; ++u) {
        mv[u] = (wv << 8) + (u << 6) + lane;
        cmv[u] = s_c[mv[u]];
    }

    // ---- pass 1: per-row min over this lane's 4 candidates; merge via atomicMin ----
#pragma unroll 4
    for (int rr = 0; rr < 16; ++rr) {
        const int nrow = nbase + rr;
        const float4 rc = s_c[nrow];       // same-address broadcast, conflict-free
        float mn = INFINITY;
#pragma unroll
        for (int u = 0; u < 4; ++u) {
            float dist = fmaxf(rc.w + cmv[u].w -
                               2.0f * (rc.x * cmv[u].x + rc.y * cmv[u].y + rc.z * cmv[u].z), 0.0f);
            mn = fminf(mn, (mv[u] == nrow) ? INFINITY : dist);
        }
        atomicMin(&s_pm[rr][lane], __float_as_uint(mn));
    }
    __syncthreads();

    // ---- tau per row: wave rr sorts its row's 64 subset minima ----
    {
        float v = __uint_as_float(s_pm[wv][lane]);
#pragma unroll
        for (int k = 2; k <= 64; k <<= 1) {
#pragma unroll
            for (int j = k >> 1; j > 0; j >>= 1) {
                float o = __shfl_xor(v, j);
                bool take_min = (((lane & j) == 0) == ((lane & k) == 0));
                v = take_min ? fminf(v, o) : fmaxf(v, o);
            }
        }
        if (lane == 15) s_tau[wv] = v;     // 16th smallest
    }
    __syncthreads();

    // ---- pass 2: append survivors from the register chunk for all 16 rows ----
#pragma unroll 4
    for (int rr = 0; rr < 16; ++rr) {
        const int nrow = nbase + rr;
        const float tau = s_tau[rr];
        const float4 rc = s_c[nrow];
#pragma unroll
        for (int u = 0; u < 4; ++u) {
            float dist = fmaxf(rc.w + cmv[u].w -
                               2.0f * (rc.x * cmv[u].x + rc.y * cmv[u].y + rc.z * cmv[u].z), 0.0f);
            if (dist <= tau && mv[u] != nrow) {
                int pos = atomicAdd(&s_cnt[rr], 1);
                if (pos < 64)
                    s_buf[rr][pos] = ((unsigned long long)__float_as_uint(dist) << 32)
                                     | (unsigned)mv[u];
            }
        }
    }
    __syncthreads();

    // ---- selection: wave rr owns row rr ----
    const int rg = r0 + wv;                // global row
    const int n = nbase + wv;              // in-batch row
    const int cnt = s_cnt[wv];

    int my_sel = -1;
    if (cnt <= 64) {
        unsigned long long key = (lane < cnt) ? s_buf[wv][lane] : ~0ull;
#pragma unroll
        for (int k = 2; k <= 64; k <<= 1) {
#pragma unroll
            for (int j = k >> 1; j > 0; j >>= 1) {
                unsigned long long o = __shfl_xor(key, j);
                bool take_min = (((lane & j) == 0) == ((lane & k) == 0));
                unsigned long long mn = (key < o) ? key : o;
                unsigned long long mx = (key < o) ? o : key;
                key = take_min ? mn : mx;
            }
        }
        if (lane < K && key != ~0ull) my_sel = (int)(unsigned)key;
    } else {
        // exact fallback: 16 rounds of full rescan-argmin over LDS table
        const float4 cq = s_c[n];
        unsigned long long removed = 0ull;
        for (int round = 0; round < K; ++round) {
            float bd = INFINITY; int bi = 0x7FFFFFFF;
            for (int j = 0; j < 64; ++j) {
                const int m = lane + (j << 6);
                float4 cm = s_c[m];
                float dist = fmaxf(cq.w + cm.w -
                                   2.0f * (cq.x * cm.x + cq.y * cm.y + cq.z * cm.z), 0.0f);
                bool skip = ((removed >> j) & 1ull) || (m == n);
                if (!skip && dist < bd) { bd = dist; bi = m; }
            }
            float md = bd;
#pragma unroll
            for (int off = 32; off; off >>= 1) md = fminf(md, __shfl_xor(md, off));
            if (md == INFINITY) break;
            int kk = (bd == md) ? bi : 0x7FFFFFFF;
#pragma unroll
            for (int off = 32; off; off >>= 1) kk = min(kk, __shfl_xor(kk, off));
            if (lane == round) my_sel = kk;
            if (kk == bi) removed |= 1ull << (bi >> 6);
        }
    }

    if (my_sel >= 0) {
        atomicOr(&adj[(size_t)rg * NW + (my_sel >> 5)], 1u << (my_sel & 31));
        atomicOr(&adj[(size_t)(gbase + my_sel) * NW + (n >> 5)], 1u << (n & 31));
    }
}

// ---------------------------------------------------------------------------
// Kernel 3: build weighted neighbor lists from adjacency bits. One block per
// row. Parallel popcount-prefix, one wave per neighbor for the 256-d cosine
// dot, wave-parallel weight sum. Fused: lanes <32 compute the initial
// softmax MOMENTS mu0 = (sum c*q, sum c^2*q) for the mean-field iterations.
__global__ void build_kernel(const float* __restrict__ feats,
                             const float4* __restrict__ centers4,
                             const float* __restrict__ invnorm,
                             const unsigned* __restrict__ adj,
                             uint2* __restrict__ nbr,
                             int* __restrict__ nbr_cnt,
                             const float* __restrict__ raw_sigma,
                             const float* __restrict__ logits,
                             float2* __restrict__ mu0) {
    const int t = threadIdx.x;
    const int lane = t & 63;
    const int wv = t >> 6;
    const int r = blockIdx.x;
    const int base = r - (r & (N - 1));

    __shared__ int    s_off[NW];
    __shared__ int    s_wtot[2];
    __shared__ int    s_list[CAP];
    __shared__ float  s_w[CAP];
    __shared__ float4 s_fq[D / 4];
    __shared__ float  s_fsum[4];

    const float4* fq4 = reinterpret_cast<const float4*>(feats) + (size_t)r * (D / 4);
    if (t < D / 4) s_fq[t] = fq4[t];

    unsigned word = 0; int pc = 0;
    if (t < NW) {
        word = adj[(size_t)r * NW + t];
        pc = __popc(word);
    }
    int sc = pc;
#pragma unroll
    for (int off = 1; off < 64; off <<= 1) {
        int o = __shfl_up(sc, off);
        if (lane >= off) sc += o;
    }
    if (t < NW && lane == 63) s_wtot[wv] = sc;
    __syncthreads();
    const int total = s_wtot[0] + s_wtot[1];
    const int cnt = total > CAP ? CAP : total;
    if (t < NW) s_off[t] = sc - pc + ((wv == 1) ? s_wtot[0] : 0);
    __syncthreads();

    if (t < NW && word) {
        int o = s_off[t];
        unsigned w2 = word;
        while (w2) {
            int bit = __ffs(w2) - 1;
            if (o < CAP) s_list[o] = t * 32 + bit;
            ++o;
            w2 &= w2 - 1;
        }
    }
    __syncthreads();

    const float rs = raw_sigma[0];
    const float sigma = fmaxf(log1pf(expf(rs)), 1e-6f);
    const float nhalf_inv_s2 = -0.5f / (sigma * sigma);

    const float inq = invnorm[r];
    const float4 cq = centers4[r];

    for (int i = wv; i < cnt; i += 4) {
        int m = s_list[i];
        int gm = base + m;
        float4 fm = reinterpret_cast<const float4*>(feats)[(size_t)gm * (D / 4) + lane];
        float4 fq = s_fq[lane];
        float p = fm.x * fq.x + fm.y * fq.y + fm.z * fq.z + fm.w * fq.w;
#pragma unroll
        for (int off = 32; off; off >>= 1) p += __shfl_xor(p, off);
        if (lane == 0) {
            float cosv = p * inq * invnorm[gm];
            float aff = fminf(fmaxf((cosv + 1.0f) * 0.5f, 0.0f), 1.0f);
            float4 cm = centers4[gm];
            float dist = fmaxf(cq.w + cm.w - 2.0f * (cq.x * cm.x + cq.y * cm.y + cq.z * cm.z), 0.0f);
            s_w[i] = expf(dist * nhalf_inv_s2) * aff;
        }
    }
    __syncthreads();

    float ps = 0.0f;
    for (int i = t; i < cnt; i += 256) ps += s_w[i];
#pragma unroll
    for (int off = 32; off; off >>= 1) ps += __shfl_xor(ps, off);
    if (lane == 0) s_fsum[wv] = ps;
    __syncthreads();
    const float inv_sum = 1.0f / fmaxf(s_fsum[0] + s_fsum[1] + s_fsum[2] + s_fsum[3], 1e-6f);

    for (int i = t; i < cnt; i += 256) {
        nbr[(size_t)r * CAP + i] = make_uint2((unsigned)s_list[i],
                                              __float_as_uint(s_w[i] * inv_sum));
    }
    if (t == 0) nbr_cnt[r] = cnt;

    // fused initial softmax moments for this row (lanes 0..31)
    if (t < C) {
        float x = logits[(size_t)r * C + t];
        float mx = x;
#pragma unroll
        for (int off = 16; off; off >>= 1) mx = fmaxf(mx, __shfl_xor(mx, off, 32));
        float e = expf(x - mx);
        const float fc = (float)t;
        float s0 = e, s1 = e * fc, s2 = e * fc * fc;
#pragma unroll
        for (int off = 16; off; off >>= 1) {
            s0 += __shfl_xor(s0, off, 32);
            s1 += __shfl_xor(s1, off, 32);
            s2 += __shfl_xor(s2, off, 32);
        }
        if (t == 0) mu0[r] = make_float2(s1 / s0, s2 / s0);
    }
}

// ---------------------------------------------------------------------------
// Kernel 4: one mean-field iteration, MOMENT-COMPRESSED. Per row only
// (mu1, mu2) float2 is gathered per neighbor (8 B vs full 128 B q vector);
// m0 accumulates the stored weights (== sum_c qn[c] exactly in real arith).
// refined = logits - smooth*(m2 - 2c*m1 + c^2*m0)/961; softmax stays in
// registers; only the new mu float2 is written (q never hits memory).
// (Separate stream-ordered launches; cooperative grid.sync does NOT survive
//  graph capture on this harness — R8 post-mortem.)
__global__ void iter_kernel(const float* __restrict__ logits,
                            const uint2* __restrict__ nbr,
                            const int* __restrict__ nbr_cnt,
                            const float2* __restrict__ mu_in,
                            float2* __restrict__ mu_out,
                            float* __restrict__ out,
                            const float* __restrict__ raw_smooth,
                            int last) {
    const int t = threadIdx.x;
    const int r = blockIdx.x * 8 + (t >> 5);
    const int c = t & 31;
    const int base = r - (r & (N - 1));
    const float smooth = log1pf(expf(raw_smooth[0]));

    const int cnt = nbr_cnt[r];
    const uint2* np = nbr + (size_t)r * CAP;

    float m0 = 0.0f, m1 = 0.0f, m2 = 0.0f;
    for (int j = c; j < cnt; j += 32) {
        uint2 e = np[j];
        float w = __uint_as_float(e.y);
        float2 mu = mu_in[base + (int)e.x];
        m0 += w;
        m1 += w * mu.x;
        m2 += w * mu.y;
    }
#pragma unroll
    for (int off = 16; off; off >>= 1) {
        m0 += __shfl_xor(m0, off, 32);
        m1 += __shfl_xor(m1, off, 32);
        m2 += __shfl_xor(m2, off, 32);
    }

    const float fc = (float)c;
    float pw = (m2 - 2.0f * fc * m1 + fc * fc * m0) * (1.0f / 961.0f);
    float refined = logits[(size_t)r * C + c] - smooth * pw;

    if (last) {
        out[(size_t)r * C + c] = refined;
        return;
    }

    float mx = refined;
#pragma unroll
    for (int off = 16; off; off >>= 1) mx = fmaxf(mx, __shfl_xor(mx, off, 32));
    float e = expf(refined - mx);
    float s0 = e, s1 = e * fc, s2 = e * fc * fc;
#pragma unroll
    for (int off = 16; off; off >>= 1) {
        s0 += __shfl_xor(s0, off, 32);
        s1 += __shfl_xor(s1, off, 32);
        s2 += __shfl_xor(s2, off, 32);
    }
    if (c == 0) mu_out[r] = make_float2(s1 / s0, s2 / s0);
}

// ---------------------------------------------------------------------------
extern "C" void kernel_launch(void* const* d_in, const int* in_sizes, int n_in,
                              void* d_out, int out_size, void* d_ws, size_t ws_size,
                              hipStream_t stream) {
    const float* logits     = (const float*)d_in[0];
    const float* rois       = (const float*)d_in[1];
    const float* feats      = (const float*)d_in[2];
    const float* raw_sigma  = (const float*)d_in[3];
    const float* raw_smooth = (const float*)d_in[4];
    float* out = (float*)d_out;

    char* ws = (char*)d_ws;
    size_t off = 0;
    auto alloc = [&](size_t bytes) -> void* {
        void* p = ws + off;
        off += (bytes + 255) & ~(size_t)255;
        return p;
    };
    float4*   centers4 = (float4*)  alloc((size_t)ROWS * sizeof(float4));
    float*    invnorm  = (float*)   alloc((size_t)ROWS * 4);
    unsigned* adj      = (unsigned*)alloc((size_t)ROWS * NW * 4);
    uint2*    nbr      = (uint2*)   alloc((size_t)ROWS * CAP * 8);
    int*      nbr_cnt  = (int*)     alloc((size_t)ROWS * 4);
    float2*   mu_a     = (float2*)  alloc((size_t)ROWS * 8);
    float2*   mu_b     = (float2*)  alloc((size_t)ROWS * 8);

    pre_kernel<<<ROWS / 4, 256, 0, stream>>>(rois, feats, centers4, invnorm, (uint2*)adj);
    knn_kernel<<<ROWS / 16, 1024, 0, stream>>>(centers4, adj);
    build_kernel<<<ROWS, 256, 0, stream>>>(feats, centers4, invnorm, adj,
                                           nbr, nbr_cnt, raw_sigma, logits, mu_a);

    float2* mi = mu_a;
    float2* mo = mu_b;
    for (int it = 0; it < 5; ++it) {
        iter_kernel<<<ROWS / 8, 256, 0, stream>>>(logits, nbr, nbr_cnt,
                                                  mi, mo, out, raw_smooth,
                                                  (it == 4) ? 1 : 0);
        float2* tmp = mi; mi = mo; mo = tmp;
    }
}